// Round 3
// baseline (224.493 us; speedup 1.0000x reference)
//
#include <hip/hip_runtime.h>
#include <math.h>

#define V 16384
#define D 256
#define NH 256
#define THREE_NH 768
#define IDIM 1024
#define LN_EPS 1e-12f

typedef short s16x8 __attribute__((ext_vector_type(8)));
typedef float f32x4 __attribute__((ext_vector_type(4)));

__device__ inline unsigned short f2bf(float f) {
    unsigned u = __float_as_uint(f);
    u += 0x7fffu + ((u >> 16) & 1u);          // RNE
    return (unsigned short)(u >> 16);
}
__device__ inline float bf2f(unsigned short s) {
    return __uint_as_float(((unsigned)s) << 16);
}
__device__ inline float bflo(unsigned v) { return __uint_as_float(v << 16); }
__device__ inline float bfhi(unsigned v) { return __uint_as_float(v & 0xffff0000u); }

// Abramowitz-Stegun 7.1.26 erf, |err| < 1.5e-7 (invisible at bf16/3e-2 tol)
__device__ inline float fast_erf(float x) {
    float ax = fabsf(x);
    float t  = 1.f / fmaf(0.3275911f, ax, 1.f);
    float p  = fmaf(fmaf(fmaf(fmaf(1.061405429f, t, -1.453152027f), t,
                              1.421413741f), t, -0.284496736f), t, 0.254829592f);
    float e  = 1.f - p * t * __expf(-ax * ax);
    return copysignf(e, x);
}

// read one 8-elem bf16 fragment (16B) for (row, chunk) from XOR-swizzled LDS tile
__device__ inline s16x8 fragld(const unsigned short* lds, int row, int chunk) {
    return *(const s16x8*)&lds[row * 64 + ((chunk ^ (row & 7)) << 3)];
}

// ---------------------------------------------------------------------------
// prep: one launch for all conversions.
// blocks [0,768): W transposes (fp32 KxN -> bf16 NxK); [768,4864): X -> bf16.
// ---------------------------------------------------------------------------
__global__ __launch_bounds__(256) void prep(const float* __restrict__ X,
                                            unsigned short* __restrict__ Xb,
                                            const float* __restrict__ Wqkv,
                                            const float* __restrict__ Wo,
                                            const float* __restrict__ Wi,
                                            const float* __restrict__ Wo2,
                                            unsigned short* __restrict__ WqkvT,
                                            unsigned short* __restrict__ WoT,
                                            unsigned short* __restrict__ WiT,
                                            unsigned short* __restrict__ Wo2T) {
    const int b = blockIdx.x, t = threadIdx.x;
    if (b >= 768) {
        int i = (b - 768) * 256 + t;
        float4 v = ((const float4*)X)[i];
        ushort4 o;
        o.x = f2bf(v.x); o.y = f2bf(v.y); o.z = f2bf(v.z); o.w = f2bf(v.w);
        ((ushort4*)Xb)[i] = o;
        return;
    }
    __shared__ float tile[32][33];
    const float* W; unsigned short* Wt; int K, N, bx, by;
    if (b < 192)      { W = Wqkv; Wt = WqkvT; K = 256;  N = 768;  bx = b & 7;          by = b >> 3; }
    else if (b < 256) { W = Wo;   Wt = WoT;   K = 256;  N = 256;  bx = (b - 192) & 7;  by = (b - 192) >> 3; }
    else if (b < 512) { W = Wi;   Wt = WiT;   K = 256;  N = 1024; bx = (b - 256) & 7;  by = (b - 256) >> 3; }
    else              { W = Wo2;  Wt = Wo2T;  K = 1024; N = 256;  bx = (b - 512) & 31; by = (b - 512) >> 5; }
    const int k0 = bx * 32, n0 = by * 32;
    #pragma unroll
    for (int p = 0; p < 4; ++p) {
        int idx = t + p * 256, r = idx >> 5, c = idx & 31;
        tile[r][c] = W[(size_t)(k0 + r) * N + n0 + c];
    }
    __syncthreads();
    #pragma unroll
    for (int p = 0; p < 4; ++p) {
        int idx = t + p * 256, r = idx >> 5, c = idx & 31;
        Wt[(size_t)(n0 + r) * K + k0 + c] = f2bf(tile[c][r]);
    }
}

// ---------------------------------------------------------------------------
// gemm_direct<K,N,EPI>: C(bf16, MxN) = A(bf16, MxK) @ Bt(bf16, NxK)^T
// NO LDS, NO BARRIERS. Both operands read as MFMA fragments directly from
// global: per wave-instruction 16 rows x 64 contiguous bytes (fully
// coalesced). B is an L2-resident shared weight (<=0.5MB); A rows are
// L1-hot within the block and XCD-banded across blocks (swizzle below), so
// HBM sees A ~once. The fully-unrolled K-loop (4 rounds) is free for the
// compiler to software-pipeline: no vmcnt(0)/s_barrier drain points.
// 128x128 tile, 4 waves of 64x64. EPI: 0 = none, 1 = gelu (fast erf).
// ---------------------------------------------------------------------------
template <int K, int N, int EPI>
__global__ __launch_bounds__(256) void gemm_direct(const unsigned short* __restrict__ A,
                                                   const unsigned short* __restrict__ Bt,
                                                   unsigned short* __restrict__ C) {
    constexpr int NCOL = N / 128;
    const int b = blockIdx.x;
    const int idx = b >> 3;
    const int r0 = ((b & 7) * 16 + idx / NCOL) * 128;   // XCD row-band swizzle
    const int c0 = (idx % NCOL) * 128;
    const int t = threadIdx.x;
    const int wv = t >> 6, lane = t & 63, q = lane >> 4, l16 = lane & 15;
    const int wr = (wv >> 1) * 64, wc = (wv & 1) * 64;
    f32x4 acc[4][4] = {};

    const unsigned short* Ap = A  + (size_t)(r0 + wr + l16) * K;
    const unsigned short* Bp = Bt + (size_t)(c0 + wc + l16) * K;

    #pragma unroll
    for (int k0 = 0; k0 < K; k0 += 64) {
        s16x8 af[4][2], bfr[4][2];
        #pragma unroll
        for (int mf = 0; mf < 4; ++mf)
            #pragma unroll
            for (int kk2 = 0; kk2 < 2; ++kk2)
                af[mf][kk2] = *(const s16x8*)&Ap[(size_t)mf * 16 * K + k0 + (kk2 * 4 + q) * 8];
        #pragma unroll
        for (int nf = 0; nf < 4; ++nf)
            #pragma unroll
            for (int kk2 = 0; kk2 < 2; ++kk2)
                bfr[nf][kk2] = *(const s16x8*)&Bp[(size_t)nf * 16 * K + k0 + (kk2 * 4 + q) * 8];
        #pragma unroll
        for (int kk2 = 0; kk2 < 2; ++kk2)
            #pragma unroll
            for (int mf = 0; mf < 4; ++mf)
                #pragma unroll
                for (int nf = 0; nf < 4; ++nf)
                    acc[mf][nf] = __builtin_amdgcn_mfma_f32_16x16x32_bf16(af[mf][kk2], bfr[nf][kk2], acc[mf][nf], 0, 0, 0);
    }

    #pragma unroll
    for (int mf = 0; mf < 4; ++mf)
        #pragma unroll
        for (int nf = 0; nf < 4; ++nf) {
            const int cg = c0 + wc + nf * 16 + l16;
            #pragma unroll
            for (int r = 0; r < 4; ++r) {
                const int rg = r0 + wr + mf * 16 + q * 4 + r;
                float v = acc[mf][nf][r];
                if (EPI == 1) v = 0.5f * v * (1.f + fast_erf(v * 0.70710678118654752f));
                C[(size_t)rg * N + cg] = f2bf(v);
            }
        }
}

// ---------------------------------------------------------------------------
// gemm_ln_direct<K,OUTF,RESBF>: out = LN(A(bf16,MxK) @ Bt(bf16,256xK)^T + res).
// BM=32, BN=256, 4 waves each 32 rows x 64 cols. GEMM is fully direct-from-
// global (no staging, no k-loop barriers); only the LN cross-wave reduction
// uses LDS. A rows shared by all 4 waves (L1-hot); B = L2-resident weight.
// ---------------------------------------------------------------------------
template <int K, bool OUTF, bool RESBF>
__global__ __launch_bounds__(256) void gemm_ln_direct(const unsigned short* __restrict__ A,
                                                      const unsigned short* __restrict__ Bt,
                                                      const void* __restrict__ resv,
                                                      const float* __restrict__ gamma,
                                                      const float* __restrict__ beta,
                                                      float* __restrict__ outf,
                                                      unsigned short* __restrict__ outb) {
    __shared__ float2 partial[4][32];
    __shared__ float2 stats[32];
    const int t = threadIdx.x, r0 = blockIdx.x * 32;
    const int wv = t >> 6, lane = t & 63, q = lane >> 4, l16 = lane & 15;
    const int wc = wv * 64;
    f32x4 acc[2][4] = {};

    const unsigned short* Ap = A  + (size_t)(r0 + l16) * K;
    const unsigned short* Bp = Bt + (size_t)(wc + l16) * K;

    #pragma unroll
    for (int k0 = 0; k0 < K; k0 += 64) {
        s16x8 af[2][2], bfr[4][2];
        #pragma unroll
        for (int mf = 0; mf < 2; ++mf)
            #pragma unroll
            for (int kk2 = 0; kk2 < 2; ++kk2)
                af[mf][kk2] = *(const s16x8*)&Ap[(size_t)mf * 16 * K + k0 + (kk2 * 4 + q) * 8];
        #pragma unroll
        for (int nf = 0; nf < 4; ++nf)
            #pragma unroll
            for (int kk2 = 0; kk2 < 2; ++kk2)
                bfr[nf][kk2] = *(const s16x8*)&Bp[(size_t)nf * 16 * K + k0 + (kk2 * 4 + q) * 8];
        #pragma unroll
        for (int kk2 = 0; kk2 < 2; ++kk2)
            #pragma unroll
            for (int mf = 0; mf < 2; ++mf)
                #pragma unroll
                for (int nf = 0; nf < 4; ++nf)
                    acc[mf][nf] = __builtin_amdgcn_mfma_f32_16x16x32_bf16(af[mf][kk2], bfr[nf][kk2], acc[mf][nf], 0, 0, 0);
    }

    // + residual (before LN stats)
    #pragma unroll
    for (int mf = 0; mf < 2; ++mf)
        #pragma unroll
        for (int nf = 0; nf < 4; ++nf) {
            const int cg = wc + nf * 16 + l16;
            #pragma unroll
            for (int r = 0; r < 4; ++r) {
                const size_t idx = (size_t)(r0 + mf * 16 + q * 4 + r) * NH + cg;
                float rv;
                if (RESBF) rv = bf2f(((const unsigned short*)resv)[idx]);
                else       rv = ((const float*)resv)[idx];
                acc[mf][nf][r] += rv;
            }
        }

    // per-row partial sums over this wave's 64 cols (reduce across 16-lane quad)
    #pragma unroll
    for (int mf = 0; mf < 2; ++mf) {
        float s[4] = {0.f, 0.f, 0.f, 0.f}, ss[4] = {0.f, 0.f, 0.f, 0.f};
        #pragma unroll
        for (int nf = 0; nf < 4; ++nf)
            #pragma unroll
            for (int r = 0; r < 4; ++r) {
                float v = acc[mf][nf][r];
                s[r] += v; ss[r] += v * v;
            }
        #pragma unroll
        for (int off = 1; off < 16; off <<= 1)
            #pragma unroll
            for (int r = 0; r < 4; ++r) {
                s[r]  += __shfl_xor(s[r],  off);
                ss[r] += __shfl_xor(ss[r], off);
            }
        if (l16 == 0)
            #pragma unroll
            for (int r = 0; r < 4; ++r)
                partial[wv][mf * 16 + q * 4 + r] = make_float2(s[r], ss[r]);
    }
    __syncthreads();
    if (t < 32) {
        float s = 0.f, ss = 0.f;
        #pragma unroll
        for (int w = 0; w < 4; ++w) { s += partial[w][t].x; ss += partial[w][t].y; }
        float mu  = s * (1.f / 256.f);
        float var = ss * (1.f / 256.f) - mu * mu;
        stats[t] = make_float2(mu, rsqrtf(var + LN_EPS));
    }
    __syncthreads();

    #pragma unroll
    for (int mf = 0; mf < 2; ++mf)
        #pragma unroll
        for (int nf = 0; nf < 4; ++nf) {
            const int cg = wc + nf * 16 + l16;
            const float g = gamma[cg], b = beta[cg];
            #pragma unroll
            for (int r = 0; r < 4; ++r) {
                const int rl = mf * 16 + q * 4 + r;
                const float2 st = stats[rl];
                float v = (acc[mf][nf][r] - st.x) * st.y * g + b;
                const size_t idx = (size_t)(r0 + rl) * NH + cg;
                if (OUTF) outf[idx] = v;
                else      outb[idx] = f2bf(v);
            }
        }
}

// ---------------------------------------------------------------------------
// FUSED attention + W_o GEMM + LN1. One block per group (32 nodes).
// Phase A (attention): qkv group tile in LDS (stride 776), register-blocked
//   scores, register softmax via shfl_xor(8/16), P via padded bf16 LDS,
//   PV -> o[4][8] in registers.
// Bridge: o written bf16 into an LDS A-tile in fragld() layout
//   (4 tiles of 32x64, XOR chunk swizzle), overlaying the dead qkv region.
// Phase B: A from LDS; WoT (128KB, L2-hot) read DIRECT from global as
//   fragments -> no staging, no k-loop barriers. Residual X (fp32), fused
//   LN, write bf16 preb.
// ---------------------------------------------------------------------------
#define LDR 776
__global__ __launch_bounds__(256) void attln(const unsigned short* __restrict__ qkv,
                                             const unsigned short* __restrict__ WoT,
                                             const float* __restrict__ X,
                                             const float* __restrict__ gamma,
                                             const float* __restrict__ beta,
                                             unsigned short* __restrict__ preb) {
    __shared__ unsigned short smem[33536 + 320];    // 24832 (s) + 8704 (pt) + stats
    unsigned short* s  = smem;                      // attn qkv tile, stride LDR
    unsigned short* pt = smem + 24832;              // P tiles, 8*32*34
    unsigned short* at = smem;                      // phase B: A tile (4 x 32x64)
    float2* partial = (float2*)(smem + 24832);      // overlays pt (dead in phase B)
    float2* stats   = (float2*)(smem + 24832 + 512);

    const int g = blockIdx.x;
    const int t = threadIdx.x;
    const int h = t >> 5, u = t & 31;
    const int ub = u & 7;          // row set: ub + 8*di
    const int us = u >> 3;         // score cols: us + 4*dj ; PV d0 = us*8
    const int qc = h * 96;         // q col base; k at +32; v at +64

    // ---- load: group's qkv is 24576 contiguous ushorts; 16B per lane ----
    const unsigned short* src = qkv + (size_t)g * 32 * THREE_NH;
    #pragma unroll
    for (int pp = 0; pp < 12; ++pp) {
        int c = t + pp * 256;                  // chunk id 0..3071
        int row = c / 96, col8 = c % 96;
        s16x8 vv = *(const s16x8*)&src[c * 8];
        *(s16x8*)&s[row * LDR + col8 * 8] = vv;
    }
    __syncthreads();

    // ---- scores ----
    float sc[4][8];
    #pragma unroll
    for (int di = 0; di < 4; ++di)
        #pragma unroll
        for (int dj = 0; dj < 8; ++dj) sc[di][dj] = 0.f;

    for (int kq = 0; kq < 8; ++kq) {
        float qv[4][4];
        #pragma unroll
        for (int di = 0; di < 4; ++di) {
            uint2 v = *(const uint2*)&s[(ub + 8 * di) * LDR + qc + 4 * kq];
            qv[di][0] = bflo(v.x); qv[di][1] = bfhi(v.x);
            qv[di][2] = bflo(v.y); qv[di][3] = bfhi(v.y);
        }
        #pragma unroll
        for (int dj = 0; dj < 8; ++dj) {
            uint2 v = *(const uint2*)&s[(us + 4 * dj) * LDR + qc + 32 + 4 * kq];
            float kv[4];
            kv[0] = bflo(v.x); kv[1] = bfhi(v.x);
            kv[2] = bflo(v.y); kv[3] = bfhi(v.y);
            #pragma unroll
            for (int di = 0; di < 4; ++di)
                #pragma unroll
                for (int kk = 0; kk < 4; ++kk)
                    sc[di][dj] = fmaf(qv[di][kk], kv[kk], sc[di][dj]);
        }
    }

    // ---- softmax per row ----
    #pragma unroll
    for (int di = 0; di < 4; ++di) {
        float m = sc[di][0];
        #pragma unroll
        for (int dj = 1; dj < 8; ++dj) m = fmaxf(m, sc[di][dj]);
        m = fmaxf(m, __shfl_xor(m, 8));
        m = fmaxf(m, __shfl_xor(m, 16));
        float sum = 0.f;
        #pragma unroll
        for (int dj = 0; dj < 8; ++dj) {
            float e = __expf((sc[di][dj] - m) * 0.17677669529663687f);
            sc[di][dj] = e;
            sum += e;
        }
        sum += __shfl_xor(sum, 8);
        sum += __shfl_xor(sum, 16);
        float inv = 1.f / sum;
        const int rb = h * 1088 + (ub + 8 * di) * 34;
        #pragma unroll
        for (int dj = 0; dj < 8; ++dj)
            pt[rb + us + 4 * dj] = f2bf(sc[di][dj] * inv);
    }
    __syncthreads();

    // ---- PV ----
    const int vc = qc + 64, d0 = us * 8;
    float o[4][8];
    #pragma unroll
    for (int di = 0; di < 4; ++di)
        #pragma unroll
        for (int dd = 0; dd < 8; ++dd) o[di][dd] = 0.f;

    for (int j = 0; j < 32; ++j) {
        float pv[4];
        #pragma unroll
        for (int di = 0; di < 4; ++di)
            pv[di] = bf2f(pt[h * 1088 + (ub + 8 * di) * 34 + j]);
        #pragma unroll
        for (int dq = 0; dq < 2; ++dq) {
            uint2 v = *(const uint2*)&s[j * LDR + vc + d0 + 4 * dq];
            float v0 = bflo(v.x), v1 = bfhi(v.x), v2 = bflo(v.y), v3 = bfhi(v.y);
            #pragma unroll
            for (int di = 0; di < 4; ++di) {
                o[di][dq * 4 + 0] = fmaf(pv[di], v0, o[di][dq * 4 + 0]);
                o[di][dq * 4 + 1] = fmaf(pv[di], v1, o[di][dq * 4 + 1]);
                o[di][dq * 4 + 2] = fmaf(pv[di], v2, o[di][dq * 4 + 2]);
                o[di][dq * 4 + 3] = fmaf(pv[di], v3, o[di][dq * 4 + 3]);
            }
        }
    }
    __syncthreads();   // all reads of s/pt done before overwriting with at

    // ---- bridge: o -> at (swizzled A layout) ----
    {
        const int col = h * 32 + d0;           // 8-col chunk this thread owns
        const int kb = col >> 6, c = (col & 63) >> 3;
        #pragma unroll
        for (int di = 0; di < 4; ++di) {
            const int i = ub + 8 * di;
            s16x8 ov;
            #pragma unroll
            for (int dd = 0; dd < 8; ++dd) ov[dd] = (short)f2bf(o[di][dd]);
            *(s16x8*)&at[kb * 2048 + i * 64 + ((c ^ (i & 7)) << 3)] = ov;
        }
    }
    __syncthreads();   // at visible to all waves before phase B reads

    // ---- phase B: pre = LN(at @ WoT^T + X), write bf16. B direct global. ----
    const int wv = t >> 6, lane = t & 63, q = lane >> 4, l16 = lane & 15;
    const int wc = wv * 64;
    const int r0 = g * 32;
    f32x4 acc[2][4] = {};

    const unsigned short* Bp = WoT + (size_t)(wc + l16) * NH;

    #pragma unroll
    for (int kc = 0; kc < 4; ++kc) {
        const unsigned short* atk = at + kc * 2048;
        #pragma unroll
        for (int kk2 = 0; kk2 < 2; ++kk2) {
            s16x8 af[2], bfr[4];
            #pragma unroll
            for (int mf = 0; mf < 2; ++mf)
                af[mf] = fragld(atk, mf * 16 + l16, kk2 * 4 + q);
            #pragma unroll
            for (int nf = 0; nf < 4; ++nf)
                bfr[nf] = *(const s16x8*)&Bp[(size_t)nf * 16 * NH + kc * 64 + (kk2 * 4 + q) * 8];
            #pragma unroll
            for (int mf = 0; mf < 2; ++mf)
                #pragma unroll
                for (int nf = 0; nf < 4; ++nf)
                    acc[mf][nf] = __builtin_amdgcn_mfma_f32_16x16x32_bf16(af[mf], bfr[nf], acc[mf][nf], 0, 0, 0);
        }
    }

    // + residual X (fp32)
    #pragma unroll
    for (int mf = 0; mf < 2; ++mf)
        #pragma unroll
        for (int nf = 0; nf < 4; ++nf) {
            const int cg = wc + nf * 16 + l16;
            #pragma unroll
            for (int r = 0; r < 4; ++r)
                acc[mf][nf][r] += X[(size_t)(r0 + mf * 16 + q * 4 + r) * NH + cg];
        }

    // LN partial sums
    #pragma unroll
    for (int mf = 0; mf < 2; ++mf) {
        float sp[4] = {0.f, 0.f, 0.f, 0.f}, ssp[4] = {0.f, 0.f, 0.f, 0.f};
        #pragma unroll
        for (int nf = 0; nf < 4; ++nf)
            #pragma unroll
            for (int r = 0; r < 4; ++r) {
                float v = acc[mf][nf][r];
                sp[r] += v; ssp[r] += v * v;
            }
        #pragma unroll
        for (int off = 1; off < 16; off <<= 1)
            #pragma unroll
            for (int r = 0; r < 4; ++r) {
                sp[r]  += __shfl_xor(sp[r],  off);
                ssp[r] += __shfl_xor(ssp[r], off);
            }
        if (l16 == 0)
            #pragma unroll
            for (int r = 0; r < 4; ++r)
                partial[wv * 32 + mf * 16 + q * 4 + r] = make_float2(sp[r], ssp[r]);
    }
    __syncthreads();
    if (t < 32) {
        float sv = 0.f, ssv = 0.f;
        #pragma unroll
        for (int w = 0; w < 4; ++w) { sv += partial[w * 32 + t].x; ssv += partial[w * 32 + t].y; }
        float mu  = sv * (1.f / 256.f);
        float var = ssv * (1.f / 256.f) - mu * mu;
        stats[t] = make_float2(mu, rsqrtf(var + LN_EPS));
    }
    __syncthreads();

    #pragma unroll
    for (int mf = 0; mf < 2; ++mf)
        #pragma unroll
        for (int nf = 0; nf < 4; ++nf) {
            const int cg = wc + nf * 16 + l16;
            const float gm = gamma[cg], bt = beta[cg];
            #pragma unroll
            for (int r = 0; r < 4; ++r) {
                const int rl = mf * 16 + q * 4 + r;
                const float2 st = stats[rl];
                float v = (acc[mf][nf][r] - st.x) * st.y * gm + bt;
                preb[(size_t)(r0 + rl) * NH + cg] = f2bf(v);
            }
        }
}

// ---------------------------------------------------------------------------
extern "C" void kernel_launch(void* const* d_in, const int* in_sizes, int n_in,
                              void* d_out, int out_size, void* d_ws, size_t ws_size,
                              hipStream_t stream) {
    const float* X      = (const float*)d_in[0];
    const float* W_qkv  = (const float*)d_in[2];
    const float* W_o    = (const float*)d_in[3];
    const float* ln1_g  = (const float*)d_in[4];
    const float* ln1_b  = (const float*)d_in[5];
    const float* W_i    = (const float*)d_in[6];
    const float* W_out2 = (const float*)d_in[7];
    const float* ln2_g  = (const float*)d_in[8];
    const float* ln2_b  = (const float*)d_in[9];
    float* out = (float*)d_out;

    char* ws = (char*)d_ws;
    unsigned short* Xbf   = (unsigned short*)(ws);                 //  8.0 MB
    unsigned short* qkvb  = (unsigned short*)(ws + 8388608);       // 25.2 MB
    unsigned short* preb  = (unsigned short*)(ws + 58720256);      //  8.0 MB
    unsigned short* WqkvT = (unsigned short*)(ws + 67108864);
    unsigned short* WoT   = (unsigned short*)(ws + 67502080);
    unsigned short* WiT   = (unsigned short*)(ws + 67633152);
    unsigned short* Wo2T  = (unsigned short*)(ws + 68157440);
    unsigned short* interb = (unsigned short*)(ws);                // 33.5 MB alias (Xbf+qkvb dead)

    dim3 blk(256);
    hipLaunchKernelGGL(prep, dim3(768 + V * D / 4 / 256), blk, 0, stream,
                       X, Xbf, W_qkv, W_o, W_i, W_out2, WqkvT, WoT, WiT, Wo2T);

    hipLaunchKernelGGL((gemm_direct<D, THREE_NH, 0>), dim3(V / 128 * (THREE_NH / 128)), blk, 0, stream,
                       Xbf, WqkvT, qkvb);
    hipLaunchKernelGGL(attln, dim3(V / 32), blk, 0, stream,
                       qkvb, WoT, X, ln1_g, ln1_b, preb);
    hipLaunchKernelGGL((gemm_direct<D, IDIM, 1>), dim3(V / 128 * (IDIM / 128)), blk, 0, stream,
                       preb, WiT, interb);
    hipLaunchKernelGGL((gemm_ln_direct<IDIM, true, true>), dim3(V / 32), blk, 0, stream,
                       interb, Wo2T, (const void*)preb, ln2_g, ln2_b, out, (unsigned short*)nullptr);
}

// Round 4
// 169.206 us; speedup vs baseline: 1.3267x; 1.3267x over previous
//
#include <hip/hip_runtime.h>
#include <math.h>

#define V 16384
#define D 256
#define NH 256
#define THREE_NH 768
#define IDIM 1024
#define LN_EPS 1e-12f

typedef short s16x8 __attribute__((ext_vector_type(8)));
typedef float f32x4 __attribute__((ext_vector_type(4)));

__device__ inline unsigned short f2bf(float f) {
    unsigned u = __float_as_uint(f);
    u += 0x7fffu + ((u >> 16) & 1u);          // RNE
    return (unsigned short)(u >> 16);
}
__device__ inline float bf2f(unsigned short s) {
    return __uint_as_float(((unsigned)s) << 16);
}
__device__ inline float bflo(unsigned v) { return __uint_as_float(v << 16); }
__device__ inline float bfhi(unsigned v) { return __uint_as_float(v & 0xffff0000u); }

// Abramowitz-Stegun 7.1.26 erf, |err| < 1.5e-7 (invisible at bf16 tol)
__device__ inline float fast_erf(float x) {
    float ax = fabsf(x);
    float t  = 1.f / fmaf(0.3275911f, ax, 1.f);
    float p  = fmaf(fmaf(fmaf(fmaf(1.061405429f, t, -1.453152027f), t,
                              1.421413741f), t, -0.284496736f), t, 0.254829592f);
    float e  = 1.f - p * t * __expf(-ax * ax);
    return copysignf(e, x);
}

// async global->LDS, 16B per lane. LDS dest = wave-uniform base + lane*16.
__device__ inline void gl2lds16(const unsigned short* g, unsigned short* l) {
    __builtin_amdgcn_global_load_lds(
        (__attribute__((address_space(1))) void*)(g),
        (__attribute__((address_space(3))) void*)(l), 16, 0, 0);
}

// Stage ROWS_T x 64 bf16 tile (row-major, leading dim ldk) into LDS.
// 16B chunk c of row r stored at chunk slot c ^ (r&7) (XOR swizzle on the
// global side; LDS write order stays lane-contiguous for global_load_lds).
template <int ROWS_T>
__device__ inline void stage(const unsigned short* __restrict__ src, size_t row0,
                             int ldk, int k0, unsigned short* lds, int wv, int lane) {
    constexpr int PER_WAVE = ROWS_T / 32;     // 1KB segments per wave
    #pragma unroll
    for (int i = 0; i < PER_WAVE; ++i) {
        const int seg = wv * PER_WAVE + i;
        const int r = seg * 8 + (lane >> 3);
        const int c = (lane & 7) ^ (r & 7);
        gl2lds16(src + (row0 + (size_t)r) * ldk + k0 + c * 8, lds + seg * 512);
    }
}

// read one 8-elem bf16 fragment (16B) for (row, chunk) from swizzled tile
__device__ inline s16x8 fragld(const unsigned short* lds, int row, int chunk) {
    return *(const s16x8*)&lds[row * 64 + ((chunk ^ (row & 7)) << 3)];
}

// ---------------------------------------------------------------------------
// prep: one launch for all conversions.
// blocks [0,768): W transposes (fp32 KxN -> bf16 NxK); [768,4864): X -> bf16.
// ---------------------------------------------------------------------------
__global__ __launch_bounds__(256) void prep(const float* __restrict__ X,
                                            unsigned short* __restrict__ Xb,
                                            const float* __restrict__ Wqkv,
                                            const float* __restrict__ Wo,
                                            const float* __restrict__ Wi,
                                            const float* __restrict__ Wo2,
                                            unsigned short* __restrict__ WqkvT,
                                            unsigned short* __restrict__ WoT,
                                            unsigned short* __restrict__ WiT,
                                            unsigned short* __restrict__ Wo2T) {
    const int b = blockIdx.x, t = threadIdx.x;
    if (b >= 768) {
        int i = (b - 768) * 256 + t;
        float4 v = ((const float4*)X)[i];
        ushort4 o;
        o.x = f2bf(v.x); o.y = f2bf(v.y); o.z = f2bf(v.z); o.w = f2bf(v.w);
        ((ushort4*)Xb)[i] = o;
        return;
    }
    __shared__ float tile[32][33];
    const float* W; unsigned short* Wt; int K, N, bx, by;
    if (b < 192)      { W = Wqkv; Wt = WqkvT; K = 256;  N = 768;  bx = b & 7;          by = b >> 3; }
    else if (b < 256) { W = Wo;   Wt = WoT;   K = 256;  N = 256;  bx = (b - 192) & 7;  by = (b - 192) >> 3; }
    else if (b < 512) { W = Wi;   Wt = WiT;   K = 256;  N = 1024; bx = (b - 256) & 7;  by = (b - 256) >> 3; }
    else              { W = Wo2;  Wt = Wo2T;  K = 1024; N = 256;  bx = (b - 512) & 31; by = (b - 512) >> 5; }
    const int k0 = bx * 32, n0 = by * 32;
    #pragma unroll
    for (int p = 0; p < 4; ++p) {
        int idx = t + p * 256, r = idx >> 5, c = idx & 31;
        tile[r][c] = W[(size_t)(k0 + r) * N + n0 + c];
    }
    __syncthreads();
    #pragma unroll
    for (int p = 0; p < 4; ++p) {
        int idx = t + p * 256, r = idx >> 5, c = idx & 31;
        Wt[(size_t)(n0 + r) * K + k0 + c] = f2bf(tile[c][r]);
    }
}

// ---------------------------------------------------------------------------
// gemm128<K,N,EPI>: C(bf16, MxN) = A(bf16, MxK) @ Bt(bf16, NxK)^T
// 128x128 tile, BK=64, 4 waves of 64x64.  2-PHASE PIPELINE: double-buffered
// LDS; each step issues the NEXT step's global_load_lds, then computes the
// current step, then drains (vmcnt(0)+barrier).  Prefetch latency hides
// under MFMA instead of being serially exposed (rounds 2/3 post-mortem).
// 1-D grid + XCD row-band swizzle for A L2-residency.
// EPI: 0 = none, 1 = gelu (fast erf).
// ---------------------------------------------------------------------------
template <int K, int N, int EPI>
__global__ __launch_bounds__(256) void gemm128(const unsigned short* __restrict__ A,
                                               const unsigned short* __restrict__ Bt,
                                               unsigned short* __restrict__ C) {
    __shared__ unsigned short As[2][128 * 64];
    __shared__ unsigned short Bs[2][128 * 64];
    constexpr int NCOL = N / 128;
    constexpr int NT = K / 64;
    const int b = blockIdx.x;
    const int idx = b >> 3;
    const int r0 = ((b & 7) * 16 + idx / NCOL) * 128;   // XCD row-band swizzle
    const int c0 = (idx % NCOL) * 128;
    const int t = threadIdx.x;
    const int wv = t >> 6, lane = t & 63, q = lane >> 4, l16 = lane & 15;
    const int wr = (wv >> 1) * 64, wc = (wv & 1) * 64;
    f32x4 acc[4][4] = {};

    stage<128>(A,  (size_t)r0, K, 0, As[0], wv, lane);
    stage<128>(Bt, (size_t)c0, K, 0, Bs[0], wv, lane);
    __builtin_amdgcn_s_waitcnt(0);
    __syncthreads();

    #pragma unroll
    for (int kt = 0; kt < NT; ++kt) {
        const int cur = kt & 1;
        if (kt + 1 < NT) {
            stage<128>(A,  (size_t)r0, K, (kt + 1) * 64, As[cur ^ 1], wv, lane);
            stage<128>(Bt, (size_t)c0, K, (kt + 1) * 64, Bs[cur ^ 1], wv, lane);
        }
        #pragma unroll
        for (int kk2 = 0; kk2 < 2; ++kk2) {
            s16x8 af[4], bfr[4];
            #pragma unroll
            for (int mf = 0; mf < 4; ++mf)
                af[mf] = fragld(As[cur], wr + mf * 16 + l16, kk2 * 4 + q);
            #pragma unroll
            for (int nf = 0; nf < 4; ++nf)
                bfr[nf] = fragld(Bs[cur], wc + nf * 16 + l16, kk2 * 4 + q);
            #pragma unroll
            for (int mf = 0; mf < 4; ++mf)
                #pragma unroll
                for (int nf = 0; nf < 4; ++nf)
                    acc[mf][nf] = __builtin_amdgcn_mfma_f32_16x16x32_bf16(af[mf], bfr[nf], acc[mf][nf], 0, 0, 0);
        }
        __builtin_amdgcn_s_waitcnt(0);   // prefetch landed + all reads of cur done
        __syncthreads();
    }

    #pragma unroll
    for (int mf = 0; mf < 4; ++mf)
        #pragma unroll
        for (int nf = 0; nf < 4; ++nf) {
            const int cg = c0 + wc + nf * 16 + l16;
            #pragma unroll
            for (int r = 0; r < 4; ++r) {
                const int rg = r0 + wr + mf * 16 + q * 4 + r;
                float v = acc[mf][nf][r];
                if (EPI == 1) v = 0.5f * v * (1.f + fast_erf(v * 0.70710678118654752f));
                C[(size_t)rg * N + cg] = f2bf(v);
            }
        }
}

// ---------------------------------------------------------------------------
// gemm_ln<K,OUTF,RESBF>: out = LN(A(bf16,MxK) @ Bt(bf16,256xK)^T + res); N=256.
// BM=32, BN=256, 4 waves each 32 rows x 64 cols; fused row LN across waves.
// BK=64, 16 steps, same 2-phase double-buffered pipeline as gemm128.
// LDS 73.25 KB -> 2 blocks/CU (grid 512 caps there anyway).
// ---------------------------------------------------------------------------
template <int K, bool OUTF, bool RESBF>
__global__ __launch_bounds__(256) void gemm_ln(const unsigned short* __restrict__ A,
                                               const unsigned short* __restrict__ Bt,
                                               const void* __restrict__ resv,
                                               const float* __restrict__ gamma,
                                               const float* __restrict__ beta,
                                               float* __restrict__ outf,
                                               unsigned short* __restrict__ outb) {
    __shared__ unsigned short As[2][32 * 64];
    __shared__ unsigned short Bs[2][256 * 64];
    __shared__ float2 partial[4][32];
    __shared__ float2 stats[32];
    constexpr int NT = K / 64;
    const int t = threadIdx.x, r0 = blockIdx.x * 32;
    const int wv = t >> 6, lane = t & 63, q = lane >> 4, l16 = lane & 15;
    const int wc = wv * 64;
    f32x4 acc[2][4] = {};

    stage<32>(A, (size_t)r0, K, 0, As[0], wv, lane);
    stage<256>(Bt, 0, K, 0, Bs[0], wv, lane);
    __builtin_amdgcn_s_waitcnt(0);
    __syncthreads();

    #pragma unroll
    for (int kt = 0; kt < NT; ++kt) {
        const int cur = kt & 1;
        if (kt + 1 < NT) {
            stage<32>(A, (size_t)r0, K, (kt + 1) * 64, As[cur ^ 1], wv, lane);
            stage<256>(Bt, 0, K, (kt + 1) * 64, Bs[cur ^ 1], wv, lane);
        }
        #pragma unroll
        for (int kk2 = 0; kk2 < 2; ++kk2) {
            s16x8 af[2], bfr[4];
            #pragma unroll
            for (int mf = 0; mf < 2; ++mf)
                af[mf] = fragld(As[cur], mf * 16 + l16, kk2 * 4 + q);
            #pragma unroll
            for (int nf = 0; nf < 4; ++nf)
                bfr[nf] = fragld(Bs[cur], wc + nf * 16 + l16, kk2 * 4 + q);
            #pragma unroll
            for (int mf = 0; mf < 2; ++mf)
                #pragma unroll
                for (int nf = 0; nf < 4; ++nf)
                    acc[mf][nf] = __builtin_amdgcn_mfma_f32_16x16x32_bf16(af[mf], bfr[nf], acc[mf][nf], 0, 0, 0);
        }
        __builtin_amdgcn_s_waitcnt(0);
        __syncthreads();
    }

    // + residual (before LN stats)
    #pragma unroll
    for (int mf = 0; mf < 2; ++mf)
        #pragma unroll
        for (int nf = 0; nf < 4; ++nf) {
            const int cg = wc + nf * 16 + l16;
            #pragma unroll
            for (int r = 0; r < 4; ++r) {
                const size_t idx = (size_t)(r0 + mf * 16 + q * 4 + r) * NH + cg;
                float rv;
                if (RESBF) rv = bf2f(((const unsigned short*)resv)[idx]);
                else       rv = ((const float*)resv)[idx];
                acc[mf][nf][r] += rv;
            }
        }

    // per-row partial sums over this wave's 64 cols (reduce across 16-lane quad)
    #pragma unroll
    for (int mf = 0; mf < 2; ++mf) {
        float s[4] = {0.f, 0.f, 0.f, 0.f}, ss[4] = {0.f, 0.f, 0.f, 0.f};
        #pragma unroll
        for (int nf = 0; nf < 4; ++nf)
            #pragma unroll
            for (int r = 0; r < 4; ++r) {
                float v = acc[mf][nf][r];
                s[r] += v; ss[r] += v * v;
            }
        #pragma unroll
        for (int off = 1; off < 16; off <<= 1)
            #pragma unroll
            for (int r = 0; r < 4; ++r) {
                s[r]  += __shfl_xor(s[r],  off);
                ss[r] += __shfl_xor(ss[r], off);
            }
        if (l16 == 0)
            #pragma unroll
            for (int r = 0; r < 4; ++r)
                partial[wv][mf * 16 + q * 4 + r] = make_float2(s[r], ss[r]);
    }
    __syncthreads();
    if (t < 32) {
        float s = 0.f, ss = 0.f;
        #pragma unroll
        for (int w = 0; w < 4; ++w) { s += partial[w][t].x; ss += partial[w][t].y; }
        float mu  = s * (1.f / 256.f);
        float var = ss * (1.f / 256.f) - mu * mu;
        stats[t] = make_float2(mu, rsqrtf(var + LN_EPS));
    }
    __syncthreads();

    #pragma unroll
    for (int mf = 0; mf < 2; ++mf)
        #pragma unroll
        for (int nf = 0; nf < 4; ++nf) {
            const int cg = wc + nf * 16 + l16;
            const float g = gamma[cg], b = beta[cg];
            #pragma unroll
            for (int r = 0; r < 4; ++r) {
                const int rl = mf * 16 + q * 4 + r;
                const float2 st = stats[rl];
                float v = (acc[mf][nf][r] - st.x) * st.y * g + b;
                const size_t idx = (size_t)(r0 + rl) * NH + cg;
                if (OUTF) outf[idx] = v;
                else      outb[idx] = f2bf(v);
            }
        }
}

// ---------------------------------------------------------------------------
// FUSED attention + W_o GEMM + LN1. One block per group (32 nodes).
// Phase A (attention): qkv group tile in LDS (stride 776), register-blocked
//   scores, register softmax via shfl_xor(8/16), P via padded bf16 LDS,
//   PV -> o[4][8] in registers.
// Bridge: o written bf16 into an LDS A-tile in fragld() layout; Bs[0]
//   (WoT k=0) prefetch issued concurrently with the bridge VALU work.
// Phase B: 2-phase double-buffered WoT staging (4 steps), fused LN.
// LDS: 40960 shorts = 80 KB exactly -> 2 blocks/CU. partial/stats overlay
//   the Bs region (dead after the last K-step's barrier).
// ---------------------------------------------------------------------------
#define LDR 776
__global__ __launch_bounds__(256) void attln(const unsigned short* __restrict__ qkv,
                                             const unsigned short* __restrict__ WoT,
                                             const float* __restrict__ X,
                                             const float* __restrict__ gamma,
                                             const float* __restrict__ beta,
                                             unsigned short* __restrict__ preb) {
    __shared__ unsigned short smem[40960];          // 80 KB
    unsigned short* s  = smem;                      // phase A: qkv tile [0,24832)
    unsigned short* pt = smem + 24832;              // phase A: P tiles [24832,33536)
    unsigned short* at = smem;                      // phase B: A tile [0,8192)
    unsigned short* Bs0 = smem + 8192;              // phase B: B dbuf0 [8192,24576)
    unsigned short* Bs1 = smem + 24576;             // phase B: B dbuf1 [24576,40960)
    float2* partial = (float2*)(smem + 8192);       // epilogue: overlays dead Bs
    float2* stats   = (float2*)(smem + 8192 + 512);

    const int g = blockIdx.x;
    const int t = threadIdx.x;
    const int h = t >> 5, u = t & 31;
    const int ub = u & 7;          // row set: ub + 8*di
    const int us = u >> 3;         // score cols: us + 4*dj ; PV d0 = us*8
    const int qc = h * 96;         // q col base; k at +32; v at +64

    // ---- load: group's qkv is 24576 contiguous ushorts; 16B per lane ----
    const unsigned short* src = qkv + (size_t)g * 32 * THREE_NH;
    #pragma unroll
    for (int pp = 0; pp < 12; ++pp) {
        int c = t + pp * 256;                  // chunk id 0..3071
        int row = c / 96, col8 = c % 96;
        s16x8 vv = *(const s16x8*)&src[c * 8];
        *(s16x8*)&s[row * LDR + col8 * 8] = vv;
    }
    __syncthreads();

    // ---- scores ----
    float sc[4][8];
    #pragma unroll
    for (int di = 0; di < 4; ++di)
        #pragma unroll
        for (int dj = 0; dj < 8; ++dj) sc[di][dj] = 0.f;

    for (int kq = 0; kq < 8; ++kq) {
        float qv[4][4];
        #pragma unroll
        for (int di = 0; di < 4; ++di) {
            uint2 v = *(const uint2*)&s[(ub + 8 * di) * LDR + qc + 4 * kq];
            qv[di][0] = bflo(v.x); qv[di][1] = bfhi(v.x);
            qv[di][2] = bflo(v.y); qv[di][3] = bfhi(v.y);
        }
        #pragma unroll
        for (int dj = 0; dj < 8; ++dj) {
            uint2 v = *(const uint2*)&s[(us + 4 * dj) * LDR + qc + 32 + 4 * kq];
            float kv[4];
            kv[0] = bflo(v.x); kv[1] = bfhi(v.x);
            kv[2] = bflo(v.y); kv[3] = bfhi(v.y);
            #pragma unroll
            for (int di = 0; di < 4; ++di)
                #pragma unroll
                for (int kk = 0; kk < 4; ++kk)
                    sc[di][dj] = fmaf(qv[di][kk], kv[kk], sc[di][dj]);
        }
    }

    // ---- softmax per row ----
    #pragma unroll
    for (int di = 0; di < 4; ++di) {
        float m = sc[di][0];
        #pragma unroll
        for (int dj = 1; dj < 8; ++dj) m = fmaxf(m, sc[di][dj]);
        m = fmaxf(m, __shfl_xor(m, 8));
        m = fmaxf(m, __shfl_xor(m, 16));
        float sum = 0.f;
        #pragma unroll
        for (int dj = 0; dj < 8; ++dj) {
            float e = __expf((sc[di][dj] - m) * 0.17677669529663687f);
            sc[di][dj] = e;
            sum += e;
        }
        sum += __shfl_xor(sum, 8);
        sum += __shfl_xor(sum, 16);
        float inv = 1.f / sum;
        const int rb = h * 1088 + (ub + 8 * di) * 34;
        #pragma unroll
        for (int dj = 0; dj < 8; ++dj)
            pt[rb + us + 4 * dj] = f2bf(sc[di][dj] * inv);
    }
    __syncthreads();

    // ---- PV ----
    const int vc = qc + 64, d0 = us * 8;
    float o[4][8];
    #pragma unroll
    for (int di = 0; di < 4; ++di)
        #pragma unroll
        for (int dd = 0; dd < 8; ++dd) o[di][dd] = 0.f;

    for (int j = 0; j < 32; ++j) {
        float pv[4];
        #pragma unroll
        for (int di = 0; di < 4; ++di)
            pv[di] = bf2f(pt[h * 1088 + (ub + 8 * di) * 34 + j]);
        #pragma unroll
        for (int dq = 0; dq < 2; ++dq) {
            uint2 v = *(const uint2*)&s[j * LDR + vc + d0 + 4 * dq];
            float v0 = bflo(v.x), v1 = bfhi(v.x), v2 = bflo(v.y), v3 = bfhi(v.y);
            #pragma unroll
            for (int di = 0; di < 4; ++di) {
                o[di][dq * 4 + 0] = fmaf(pv[di], v0, o[di][dq * 4 + 0]);
                o[di][dq * 4 + 1] = fmaf(pv[di], v1, o[di][dq * 4 + 1]);
                o[di][dq * 4 + 2] = fmaf(pv[di], v2, o[di][dq * 4 + 2]);
                o[di][dq * 4 + 3] = fmaf(pv[di], v3, o[di][dq * 4 + 3]);
            }
        }
    }
    __syncthreads();   // all reads of s/pt done before overwriting

    // ---- bridge: prefetch Bs[0] + write o -> at (swizzled A layout) ----
    const int wv = t >> 6, lane = t & 63, q = lane >> 4, l16 = lane & 15;
    stage<256>(WoT, 0, 256, 0, Bs0, wv, lane);   // overlaps bridge VALU work
    {
        const int col = h * 32 + d0;           // 8-col chunk this thread owns
        const int kb = col >> 6, c = (col & 63) >> 3;
        #pragma unroll
        for (int di = 0; di < 4; ++di) {
            const int i = ub + 8 * di;
            s16x8 ov;
            #pragma unroll
            for (int dd = 0; dd < 8; ++dd) ov[dd] = (short)f2bf(o[di][dd]);
            *(s16x8*)&at[kb * 2048 + i * 64 + ((c ^ (i & 7)) << 3)] = ov;
        }
    }
    __builtin_amdgcn_s_waitcnt(0);
    __syncthreads();   // at + Bs0 visible to all waves

    // ---- phase B: pre = LN(at @ WoT^T + X), 2-phase dbuf B staging ----
    const int wc = wv * 64;
    const int r0 = g * 32;
    f32x4 acc[2][4] = {};

    #pragma unroll
    for (int kc = 0; kc < 4; ++kc) {
        unsigned short* Bcur = (kc & 1) ? Bs1 : Bs0;
        if (kc + 1 < 4) {
            unsigned short* Bnxt = (kc & 1) ? Bs0 : Bs1;
            stage<256>(WoT, 0, 256, (kc + 1) * 64, Bnxt, wv, lane);
        }
        const unsigned short* atk = at + kc * 2048;
        #pragma unroll
        for (int kk2 = 0; kk2 < 2; ++kk2) {
            s16x8 af[2], bfr[4];
            #pragma unroll
            for (int mf = 0; mf < 2; ++mf)
                af[mf] = fragld(atk, mf * 16 + l16, kk2 * 4 + q);
            #pragma unroll
            for (int nf = 0; nf < 4; ++nf)
                bfr[nf] = fragld(Bcur, wc + nf * 16 + l16, kk2 * 4 + q);
            #pragma unroll
            for (int mf = 0; mf < 2; ++mf)
                #pragma unroll
                for (int nf = 0; nf < 4; ++nf)
                    acc[mf][nf] = __builtin_amdgcn_mfma_f32_16x16x32_bf16(af[mf], bfr[nf], acc[mf][nf], 0, 0, 0);
        }
        __builtin_amdgcn_s_waitcnt(0);
        __syncthreads();
    }

    // + residual X (fp32)
    #pragma unroll
    for (int mf = 0; mf < 2; ++mf)
        #pragma unroll
        for (int nf = 0; nf < 4; ++nf) {
            const int cg = wc + nf * 16 + l16;
            #pragma unroll
            for (int r = 0; r < 4; ++r)
                acc[mf][nf][r] += X[(size_t)(r0 + mf * 16 + q * 4 + r) * NH + cg];
        }

    // LN partial sums (partial/stats overlay Bs region — dead now)
    #pragma unroll
    for (int mf = 0; mf < 2; ++mf) {
        float sp[4] = {0.f, 0.f, 0.f, 0.f}, ssp[4] = {0.f, 0.f, 0.f, 0.f};
        #pragma unroll
        for (int nf = 0; nf < 4; ++nf)
            #pragma unroll
            for (int r = 0; r < 4; ++r) {
                float v = acc[mf][nf][r];
                sp[r] += v; ssp[r] += v * v;
            }
        #pragma unroll
        for (int off = 1; off < 16; off <<= 1)
            #pragma unroll
            for (int r = 0; r < 4; ++r) {
                sp[r]  += __shfl_xor(sp[r],  off);
                ssp[r] += __shfl_xor(ssp[r], off);
            }
        if (l16 == 0)
            #pragma unroll
            for (int r = 0; r < 4; ++r)
                partial[wv * 32 + mf * 16 + q * 4 + r] = make_float2(sp[r], ssp[r]);
    }
    __syncthreads();
    if (t < 32) {
        float sv = 0.f, ssv = 0.f;
        #pragma unroll
        for (int w = 0; w < 4; ++w) { sv += partial[w * 32 + t].x; ssv += partial[w * 32 + t].y; }
        float mu  = sv * (1.f / 256.f);
        float var = ssv * (1.f / 256.f) - mu * mu;
        stats[t] = make_float2(mu, rsqrtf(var + LN_EPS));
    }
    __syncthreads();

    #pragma unroll
    for (int mf = 0; mf < 2; ++mf)
        #pragma unroll
        for (int nf = 0; nf < 4; ++nf) {
            const int cg = wc + nf * 16 + l16;
            const float gm = gamma[cg], bt = beta[cg];
            #pragma unroll
            for (int r = 0; r < 4; ++r) {
                const int rl = mf * 16 + q * 4 + r;
                const float2 st = stats[rl];
                float v = (acc[mf][nf][r] - st.x) * st.y * gm + bt;
                preb[(size_t)(r0 + rl) * NH + cg] = f2bf(v);
            }
        }
}

// ---------------------------------------------------------------------------
extern "C" void kernel_launch(void* const* d_in, const int* in_sizes, int n_in,
                              void* d_out, int out_size, void* d_ws, size_t ws_size,
                              hipStream_t stream) {
    const float* X      = (const float*)d_in[0];
    const float* W_qkv  = (const float*)d_in[2];
    const float* W_o    = (const float*)d_in[3];
    const float* ln1_g  = (const float*)d_in[4];
    const float* ln1_b  = (const float*)d_in[5];
    const float* W_i    = (const float*)d_in[6];
    const float* W_out2 = (const float*)d_in[7];
    const float* ln2_g  = (const float*)d_in[8];
    const float* ln2_b  = (const float*)d_in[9];
    float* out = (float*)d_out;

    char* ws = (char*)d_ws;
    unsigned short* Xbf   = (unsigned short*)(ws);                 //  8.0 MB
    unsigned short* qkvb  = (unsigned short*)(ws + 8388608);       // 25.2 MB
    unsigned short* preb  = (unsigned short*)(ws + 58720256);      //  8.0 MB
    unsigned short* WqkvT = (unsigned short*)(ws + 67108864);
    unsigned short* WoT   = (unsigned short*)(ws + 67502080);
    unsigned short* WiT   = (unsigned short*)(ws + 67633152);
    unsigned short* Wo2T  = (unsigned short*)(ws + 68157440);
    unsigned short* interb = (unsigned short*)(ws);                // 33.5 MB alias (Xbf+qkvb dead)

    dim3 blk(256);
    hipLaunchKernelGGL(prep, dim3(768 + V * D / 4 / 256), blk, 0, stream,
                       X, Xbf, W_qkv, W_o, W_i, W_out2, WqkvT, WoT, WiT, Wo2T);

    hipLaunchKernelGGL((gemm128<D, THREE_NH, 0>), dim3(V / 128 * (THREE_NH / 128)), blk, 0, stream,
                       Xbf, WqkvT, qkvb);
    hipLaunchKernelGGL(attln, dim3(V / 32), blk, 0, stream,
                       qkvb, WoT, X, ln1_g, ln1_b, preb);
    hipLaunchKernelGGL((gemm128<D, IDIM, 1>), dim3(V / 128 * (IDIM / 128)), blk, 0, stream,
                       preb, WiT, interb);
    hipLaunchKernelGGL((gemm_ln<IDIM, true, true>), dim3(V / 32), blk, 0, stream,
                       interb, Wo2T, (const void*)preb, ln2_g, ln2_b, out, (unsigned short*)nullptr);
}

// Round 5
// 160.307 us; speedup vs baseline: 1.4004x; 1.0555x over previous
//
#include <hip/hip_runtime.h>
#include <math.h>

#define V 16384
#define D 256
#define NH 256
#define THREE_NH 768
#define IDIM 1024
#define LN_EPS 1e-12f
#define SCL 0.17677669529663687f

typedef short s16x8 __attribute__((ext_vector_type(8)));
typedef float f32x4 __attribute__((ext_vector_type(4)));

__device__ inline unsigned short f2bf(float f) {
    unsigned u = __float_as_uint(f);
    u += 0x7fffu + ((u >> 16) & 1u);          // RNE
    return (unsigned short)(u >> 16);
}
__device__ inline float bf2f(unsigned short s) {
    return __uint_as_float(((unsigned)s) << 16);
}

// Abramowitz-Stegun 7.1.26 erf, |err| < 1.5e-7 (invisible at bf16 tol)
__device__ inline float fast_erf(float x) {
    float ax = fabsf(x);
    float t  = 1.f / fmaf(0.3275911f, ax, 1.f);
    float p  = fmaf(fmaf(fmaf(fmaf(1.061405429f, t, -1.453152027f), t,
                              1.421413741f), t, -0.284496736f), t, 0.254829592f);
    float e  = 1.f - p * t * __expf(-ax * ax);
    return copysignf(e, x);
}

// async global->LDS, 16B per lane. LDS dest = wave-uniform base + lane*16.
__device__ inline void gl2lds16(const unsigned short* g, unsigned short* l) {
    __builtin_amdgcn_global_load_lds(
        (__attribute__((address_space(1))) void*)(g),
        (__attribute__((address_space(3))) void*)(l), 16, 0, 0);
}

// Stage ROWS_T x 64 bf16 tile (row-major, leading dim ldk) into LDS.
// 16B chunk c of row r stored at chunk slot c ^ (r&7).
template <int ROWS_T>
__device__ inline void stage(const unsigned short* __restrict__ src, size_t row0,
                             int ldk, int k0, unsigned short* lds, int wv, int lane) {
    constexpr int PER_WAVE = ROWS_T / 32;     // 1KB segments per wave
    #pragma unroll
    for (int i = 0; i < PER_WAVE; ++i) {
        const int seg = wv * PER_WAVE + i;
        const int r = seg * 8 + (lane >> 3);
        const int c = (lane & 7) ^ (r & 7);
        gl2lds16(src + (row0 + (size_t)r) * ldk + k0 + c * 8, lds + seg * 512);
    }
}

// read one 8-elem bf16 fragment (16B) for (row, chunk) from swizzled tile
__device__ inline s16x8 fragld(const unsigned short* lds, int row, int chunk) {
    return *(const s16x8*)&lds[row * 64 + ((chunk ^ (row & 7)) << 3)];
}

// ---------------------------------------------------------------------------
// prep: one launch for all conversions.
// ---------------------------------------------------------------------------
__global__ __launch_bounds__(256) void prep(const float* __restrict__ X,
                                            unsigned short* __restrict__ Xb,
                                            const float* __restrict__ Wqkv,
                                            const float* __restrict__ Wo,
                                            const float* __restrict__ Wi,
                                            const float* __restrict__ Wo2,
                                            unsigned short* __restrict__ WqkvT,
                                            unsigned short* __restrict__ WoT,
                                            unsigned short* __restrict__ WiT,
                                            unsigned short* __restrict__ Wo2T) {
    const int b = blockIdx.x, t = threadIdx.x;
    if (b >= 768) {
        int i = (b - 768) * 256 + t;
        float4 v = ((const float4*)X)[i];
        ushort4 o;
        o.x = f2bf(v.x); o.y = f2bf(v.y); o.z = f2bf(v.z); o.w = f2bf(v.w);
        ((ushort4*)Xb)[i] = o;
        return;
    }
    __shared__ float tile[32][33];
    const float* W; unsigned short* Wt; int K, N, bx, by;
    if (b < 192)      { W = Wqkv; Wt = WqkvT; K = 256;  N = 768;  bx = b & 7;          by = b >> 3; }
    else if (b < 256) { W = Wo;   Wt = WoT;   K = 256;  N = 256;  bx = (b - 192) & 7;  by = (b - 192) >> 3; }
    else if (b < 512) { W = Wi;   Wt = WiT;   K = 256;  N = 1024; bx = (b - 256) & 7;  by = (b - 256) >> 3; }
    else              { W = Wo2;  Wt = Wo2T;  K = 1024; N = 256;  bx = (b - 512) & 31; by = (b - 512) >> 5; }
    const int k0 = bx * 32, n0 = by * 32;
    #pragma unroll
    for (int p = 0; p < 4; ++p) {
        int idx = t + p * 256, r = idx >> 5, c = idx & 31;
        tile[r][c] = W[(size_t)(k0 + r) * N + n0 + c];
    }
    __syncthreads();
    #pragma unroll
    for (int p = 0; p < 4; ++p) {
        int idx = t + p * 256, r = idx >> 5, c = idx & 31;
        Wt[(size_t)(n0 + r) * K + k0 + c] = f2bf(tile[c][r]);
    }
}

// ---------------------------------------------------------------------------
// gemm128<K,N,EPI>: C = A @ Bt^T.  128x128 tile, BK=64, single-buffered,
// XCD row-band swizzle (R2-verified structure, best so far).
// ---------------------------------------------------------------------------
template <int K, int N, int EPI>
__global__ __launch_bounds__(256) void gemm128(const unsigned short* __restrict__ A,
                                               const unsigned short* __restrict__ Bt,
                                               unsigned short* __restrict__ C) {
    __shared__ unsigned short As[128 * 64];
    __shared__ unsigned short Bs[128 * 64];
    constexpr int NCOL = N / 128;
    const int b = blockIdx.x;
    const int idx = b >> 3;
    const int r0 = ((b & 7) * 16 + idx / NCOL) * 128;
    const int c0 = (idx % NCOL) * 128;
    const int t = threadIdx.x;
    const int wv = t >> 6, lane = t & 63, q = lane >> 4, l16 = lane & 15;
    const int wr = (wv >> 1) * 64, wc = (wv & 1) * 64;
    f32x4 acc[4][4] = {};

    for (int k0 = 0; k0 < K; k0 += 64) {
        __syncthreads();
        stage<128>(A,  (size_t)r0, K, k0, As, wv, lane);
        stage<128>(Bt, (size_t)c0, K, k0, Bs, wv, lane);
        __builtin_amdgcn_s_waitcnt(0);
        __syncthreads();
        #pragma unroll
        for (int kk2 = 0; kk2 < 2; ++kk2) {
            s16x8 af[4], bfr[4];
            #pragma unroll
            for (int mf = 0; mf < 4; ++mf)
                af[mf] = fragld(As, wr + mf * 16 + l16, kk2 * 4 + q);
            #pragma unroll
            for (int nf = 0; nf < 4; ++nf)
                bfr[nf] = fragld(Bs, wc + nf * 16 + l16, kk2 * 4 + q);
            #pragma unroll
            for (int mf = 0; mf < 4; ++mf)
                #pragma unroll
                for (int nf = 0; nf < 4; ++nf)
                    acc[mf][nf] = __builtin_amdgcn_mfma_f32_16x16x32_bf16(af[mf], bfr[nf], acc[mf][nf], 0, 0, 0);
        }
    }

    #pragma unroll
    for (int mf = 0; mf < 4; ++mf)
        #pragma unroll
        for (int nf = 0; nf < 4; ++nf) {
            const int cg = c0 + wc + nf * 16 + l16;
            #pragma unroll
            for (int r = 0; r < 4; ++r) {
                const int rg = r0 + wr + mf * 16 + q * 4 + r;
                float v = acc[mf][nf][r];
                if (EPI == 1) v = 0.5f * v * (1.f + fast_erf(v * 0.70710678118654752f));
                C[(size_t)rg * N + cg] = f2bf(v);
            }
        }
}

// ---------------------------------------------------------------------------
// gemm_ln<K,OUTF,RESBF>: out = LN(A @ Bt^T + res); N=256. BM=32, BN=256,
// BK=128 two-subtile rounds (R2-verified).
// ---------------------------------------------------------------------------
template <int K, bool OUTF, bool RESBF>
__global__ __launch_bounds__(256) void gemm_ln(const unsigned short* __restrict__ A,
                                               const unsigned short* __restrict__ Bt,
                                               const void* __restrict__ resv,
                                               const float* __restrict__ gamma,
                                               const float* __restrict__ beta,
                                               float* __restrict__ outf,
                                               unsigned short* __restrict__ outb) {
    __shared__ unsigned short As[2][32 * 64];
    __shared__ unsigned short Bs[2][256 * 64];
    __shared__ float2 partial[4][32];
    __shared__ float2 stats[32];
    const int t = threadIdx.x, r0 = blockIdx.x * 32;
    const int wv = t >> 6, lane = t & 63, q = lane >> 4, l16 = lane & 15;
    const int wc = wv * 64;
    f32x4 acc[2][4] = {};

    for (int k0 = 0; k0 < K; k0 += 128) {
        __syncthreads();
        stage<32>(A, (size_t)r0, K, k0,      As[0], wv, lane);
        stage<32>(A, (size_t)r0, K, k0 + 64, As[1], wv, lane);
        stage<256>(Bt, 0, K, k0,      Bs[0], wv, lane);
        stage<256>(Bt, 0, K, k0 + 64, Bs[1], wv, lane);
        __builtin_amdgcn_s_waitcnt(0);
        __syncthreads();
        #pragma unroll
        for (int sub = 0; sub < 2; ++sub) {
            #pragma unroll
            for (int kk2 = 0; kk2 < 2; ++kk2) {
                s16x8 af[2], bfr[4];
                #pragma unroll
                for (int mf = 0; mf < 2; ++mf)
                    af[mf] = fragld(As[sub], mf * 16 + l16, kk2 * 4 + q);
                #pragma unroll
                for (int nf = 0; nf < 4; ++nf)
                    bfr[nf] = fragld(Bs[sub], wc + nf * 16 + l16, kk2 * 4 + q);
                #pragma unroll
                for (int mf = 0; mf < 2; ++mf)
                    #pragma unroll
                    for (int nf = 0; nf < 4; ++nf)
                        acc[mf][nf] = __builtin_amdgcn_mfma_f32_16x16x32_bf16(af[mf], bfr[nf], acc[mf][nf], 0, 0, 0);
            }
        }
    }

    #pragma unroll
    for (int mf = 0; mf < 2; ++mf)
        #pragma unroll
        for (int nf = 0; nf < 4; ++nf) {
            const int cg = wc + nf * 16 + l16;
            #pragma unroll
            for (int r = 0; r < 4; ++r) {
                const size_t idx = (size_t)(r0 + mf * 16 + q * 4 + r) * NH + cg;
                float rv;
                if (RESBF) rv = bf2f(((const unsigned short*)resv)[idx]);
                else       rv = ((const float*)resv)[idx];
                acc[mf][nf][r] += rv;
            }
        }

    #pragma unroll
    for (int mf = 0; mf < 2; ++mf) {
        float s[4] = {0.f, 0.f, 0.f, 0.f}, ss[4] = {0.f, 0.f, 0.f, 0.f};
        #pragma unroll
        for (int nf = 0; nf < 4; ++nf)
            #pragma unroll
            for (int r = 0; r < 4; ++r) {
                float v = acc[mf][nf][r];
                s[r] += v; ss[r] += v * v;
            }
        #pragma unroll
        for (int off = 1; off < 16; off <<= 1)
            #pragma unroll
            for (int r = 0; r < 4; ++r) {
                s[r]  += __shfl_xor(s[r],  off);
                ss[r] += __shfl_xor(ss[r], off);
            }
        if (l16 == 0)
            #pragma unroll
            for (int r = 0; r < 4; ++r)
                partial[wv][mf * 16 + q * 4 + r] = make_float2(s[r], ss[r]);
    }
    __syncthreads();
    if (t < 32) {
        float s = 0.f, ss = 0.f;
        #pragma unroll
        for (int w = 0; w < 4; ++w) { s += partial[w][t].x; ss += partial[w][t].y; }
        float mu  = s * (1.f / 256.f);
        float var = ss * (1.f / 256.f) - mu * mu;
        stats[t] = make_float2(mu, rsqrtf(var + LN_EPS));
    }
    __syncthreads();

    #pragma unroll
    for (int mf = 0; mf < 2; ++mf)
        #pragma unroll
        for (int nf = 0; nf < 4; ++nf) {
            const int cg = wc + nf * 16 + l16;
            const float g = gamma[cg], b = beta[cg];
            #pragma unroll
            for (int r = 0; r < 4; ++r) {
                const int rl = mf * 16 + q * 4 + r;
                const float2 st = stats[rl];
                float v = (acc[mf][nf][r] - st.x) * st.y * g + b;
                const size_t idx = (size_t)(r0 + rl) * NH + cg;
                if (OUTF) outf[idx] = v;
                else      outb[idx] = f2bf(v);
            }
        }
}

// ---------------------------------------------------------------------------
// FUSED attention + W_o GEMM + LN1 — MFMA phase A.
// One block per group (32 nodes), 4 waves, 2 heads/wave.
// Frag convention (verified by the GEMMs above):
//   A-frag: lane holds row=l16(+16*mf), k-elems q*8..+8 (16B contiguous)
//   B-frag: lane holds out-col=l16(+16*nf), same k-elems
//   C/D:    row = mf*16 + q*4 + r, col = nf*16 + l16
// Phase A:
//   Q-frags direct from global (L2-hot, issued at entry).
//   K staged linear [h][j][k] via global_load_lds.
//   V staged transposed [h][d][j] (reg scatter), chunk swizzle (j>>3)^((d>>2)&3).
//   S = QK^T: 4 MFMA/head. Softmax on C-layout: per-lane max/sum over nf +
//   shfl_xor(1,2,4,8) across the 16-lane quad; denominator DEFERRED (P = e,
//   O *= 1/sum at the end). P transposed via LDS (chunk^q write, chunk^((l16>>2)&3) read).
//   PV: 4 MFMA/head.
// Bridge: O*inv -> at (fragld layout). Phase B: R2-verified W_o GEMM + LN.
// LDS: phase A K 16K + Vt 16K + P 16K = 48K; phase B at 16K? no: at 8K + Bs 32K
//      (overlay); + partial/stats 1.3K -> 50.4 KB total.
// ---------------------------------------------------------------------------
__global__ __launch_bounds__(256) void attln(const unsigned short* __restrict__ qkv,
                                             const unsigned short* __restrict__ WoT,
                                             const float* __restrict__ X,
                                             const float* __restrict__ gamma,
                                             const float* __restrict__ beta,
                                             unsigned short* __restrict__ preb) {
    __shared__ unsigned short smem[25216];
    unsigned short* Ks = smem;                 // [0, 8192): h*1024 + j*32 + c*8
    unsigned short* Vt = smem + 8192;          // [8192,16384): h*1024 + d*32 + swz
    unsigned short* Ps = smem + 16384;         // [16384,24576): h*1024 + row*32 + swz
    unsigned short* at = smem;                 // phase B A-tile (overlays Ks)
    unsigned short* Bs = smem + 8192;          // phase B B-stage (overlays Vt+Ps)
    float2* partial = (float2*)(smem + 24576);
    float2* stats   = (float2*)(smem + 24576 + 512);

    const int g = blockIdx.x, t = threadIdx.x;
    const int wv = t >> 6, lane = t & 63, q = lane >> 4, l16 = lane & 15;
    const unsigned short* src = qkv + (size_t)g * 32 * THREE_NH;

    // ---- Q fragments direct from global (used after barrier) ----
    s16x8 qf[2][2];
    #pragma unroll
    for (int hh = 0; hh < 2; ++hh)
        #pragma unroll
        for (int mf = 0; mf < 2; ++mf)
            qf[hh][mf] = *(const s16x8*)&src[(size_t)(mf * 16 + l16) * THREE_NH +
                                             (wv * 2 + hh) * 96 + q * 8];

    // ---- V 16B chunks to regs (transposed scatter below) ----
    s16x8 vld[4];
    int vh[4], vj[4], vdc[4];
    #pragma unroll
    for (int i = 0; i < 4; ++i) {
        int cid = i * 256 + t;
        vh[i] = cid >> 7; int rem = cid & 127; vj[i] = rem >> 2; vdc[i] = rem & 3;
        vld[i] = *(const s16x8*)&src[(size_t)vj[i] * THREE_NH + vh[i] * 96 + 64 + vdc[i] * 8];
    }

    // ---- K async global->LDS (linear dest = chunkid*16B) ----
    #pragma unroll
    for (int i = 0; i < 4; ++i) {
        int ck = (wv * 4 + i) * 64 + lane;
        int h = ck >> 7, j = (ck >> 2) & 31, c = ck & 3;
        gl2lds16(src + (size_t)j * THREE_NH + h * 96 + 32 + c * 8, Ks + (wv * 4 + i) * 512);
    }

    // ---- Vt scatter: Vt[h][d][j], chunk slot (j>>3) ^ ((d>>2)&3) ----
    #pragma unroll
    for (int i = 0; i < 4; ++i)
        #pragma unroll
        for (int e = 0; e < 8; ++e) {
            int d = vdc[i] * 8 + e;
            Vt[vh[i] * 1024 + d * 32 + ((((vj[i] >> 3) ^ ((d >> 2) & 3))) << 3) + (vj[i] & 7)] =
                (unsigned short)vld[i][e];
        }

    __builtin_amdgcn_s_waitcnt(0);
    __syncthreads();

    // ---- scores: S[h] = Q @ K^T (4 MFMA per head) ----
    f32x4 sacc[2][2][2] = {};
    #pragma unroll
    for (int hh = 0; hh < 2; ++hh) {
        const int h = wv * 2 + hh;
        #pragma unroll
        for (int nf = 0; nf < 2; ++nf) {
            s16x8 kf = *(const s16x8*)&Ks[h * 1024 + (nf * 16 + l16) * 32 + q * 8];
            #pragma unroll
            for (int mf = 0; mf < 2; ++mf)
                sacc[hh][mf][nf] = __builtin_amdgcn_mfma_f32_16x16x32_bf16(
                    qf[hh][mf], kf, sacc[hh][mf][nf], 0, 0, 0);
        }
    }

    // ---- softmax (rows in C-layout), deferred denominator ----
    float inv[2][2][4];
    #pragma unroll
    for (int hh = 0; hh < 2; ++hh) {
        const int h = wv * 2 + hh;
        #pragma unroll
        for (int mf = 0; mf < 2; ++mf)
            #pragma unroll
            for (int r = 0; r < 4; ++r) {
                float a0 = sacc[hh][mf][0][r], a1 = sacc[hh][mf][1][r];
                float m = fmaxf(a0, a1);
                m = fmaxf(m, __shfl_xor(m, 1));
                m = fmaxf(m, __shfl_xor(m, 2));
                m = fmaxf(m, __shfl_xor(m, 4));
                m = fmaxf(m, __shfl_xor(m, 8));
                float e0 = __expf((a0 - m) * SCL);
                float e1 = __expf((a1 - m) * SCL);
                float sm = e0 + e1;
                sm += __shfl_xor(sm, 1);
                sm += __shfl_xor(sm, 2);
                sm += __shfl_xor(sm, 4);
                sm += __shfl_xor(sm, 8);
                inv[hh][mf][r] = 1.f / sm;
                const int row = mf * 16 + q * 4 + r;      // (row>>2)&3 == q
                const int base = h * 1024 + row * 32 + (l16 & 7);
                Ps[base + ((((l16 >> 3) ^ q)) << 3)]       = f2bf(e0);  // col nf=0
                Ps[base + ((((2 + (l16 >> 3)) ^ q)) << 3)] = f2bf(e1);  // col nf=1
            }
    }
    // P written and read by the same wave; LDS ops are in-order per wave.

    // ---- PV: O[h] = P @ V (4 MFMA per head) ----
    f32x4 oacc[2][2][2] = {};
    #pragma unroll
    for (int hh = 0; hh < 2; ++hh) {
        const int h = wv * 2 + hh;
        const int sw = (l16 >> 2) & 3;
        s16x8 pa[2], vb[2];
        #pragma unroll
        for (int mf = 0; mf < 2; ++mf)
            pa[mf] = *(const s16x8*)&Ps[h * 1024 + (mf * 16 + l16) * 32 + ((q ^ sw) << 3)];
        #pragma unroll
        for (int nf = 0; nf < 2; ++nf)
            vb[nf] = *(const s16x8*)&Vt[h * 1024 + (nf * 16 + l16) * 32 + ((q ^ sw) << 3)];
        #pragma unroll
        for (int mf = 0; mf < 2; ++mf)
            #pragma unroll
            for (int nf = 0; nf < 2; ++nf)
                oacc[hh][mf][nf] = __builtin_amdgcn_mfma_f32_16x16x32_bf16(
                    pa[mf], vb[nf], oacc[hh][mf][nf], 0, 0, 0);
    }
    __syncthreads();   // all K/Vt/Ps reads done before at/Bs overwrite

    // ---- bridge: O * inv -> at (fragld layout) ----
    #pragma unroll
    for (int hh = 0; hh < 2; ++hh)
        #pragma unroll
        for (int mf = 0; mf < 2; ++mf)
            #pragma unroll
            for (int nf = 0; nf < 2; ++nf)
                #pragma unroll
                for (int r = 0; r < 4; ++r) {
                    float val = oacc[hh][mf][nf][r] * inv[hh][mf][r];
                    const int i = mf * 16 + q * 4 + r;
                    const int col = (wv * 2 + hh) * 32 + nf * 16 + l16;
                    const int kb = col >> 6, c = (col >> 3) & 7;
                    at[kb * 2048 + i * 64 + ((c ^ (i & 7)) << 3) + (col & 7)] = f2bf(val);
                }
    // no barrier needed here: phase-B loop opens with __syncthreads()

    // ---- phase B: pre = LN(at @ WoT^T + X), write bf16 (R2-verified) ----
    const int wc = wv * 64;
    const int r0 = g * 32;
    f32x4 acc[2][4] = {};

    for (int k0 = 0; k0 < 256; k0 += 64) {
        __syncthreads();
        stage<256>(WoT, 0, 256, k0, Bs, wv, lane);
        __builtin_amdgcn_s_waitcnt(0);
        __syncthreads();
        const unsigned short* atk = at + (k0 >> 6) * 2048;
        #pragma unroll
        for (int kk2 = 0; kk2 < 2; ++kk2) {
            s16x8 af[2], bfr[4];
            #pragma unroll
            for (int mf = 0; mf < 2; ++mf)
                af[mf] = fragld(atk, mf * 16 + l16, kk2 * 4 + q);
            #pragma unroll
            for (int nf = 0; nf < 4; ++nf)
                bfr[nf] = fragld(Bs, wc + nf * 16 + l16, kk2 * 4 + q);
            #pragma unroll
            for (int mf = 0; mf < 2; ++mf)
                #pragma unroll
                for (int nf = 0; nf < 4; ++nf)
                    acc[mf][nf] = __builtin_amdgcn_mfma_f32_16x16x32_bf16(af[mf], bfr[nf], acc[mf][nf], 0, 0, 0);
        }
    }

    // + residual X (fp32)
    #pragma unroll
    for (int mf = 0; mf < 2; ++mf)
        #pragma unroll
        for (int nf = 0; nf < 4; ++nf) {
            const int cg = wc + nf * 16 + l16;
            #pragma unroll
            for (int r = 0; r < 4; ++r)
                acc[mf][nf][r] += X[(size_t)(r0 + mf * 16 + q * 4 + r) * NH + cg];
        }

    // LN partial sums
    #pragma unroll
    for (int mf = 0; mf < 2; ++mf) {
        float sp[4] = {0.f, 0.f, 0.f, 0.f}, ssp[4] = {0.f, 0.f, 0.f, 0.f};
        #pragma unroll
        for (int nf = 0; nf < 4; ++nf)
            #pragma unroll
            for (int r = 0; r < 4; ++r) {
                float v = acc[mf][nf][r];
                sp[r] += v; ssp[r] += v * v;
            }
        #pragma unroll
        for (int off = 1; off < 16; off <<= 1)
            #pragma unroll
            for (int r = 0; r < 4; ++r) {
                sp[r]  += __shfl_xor(sp[r],  off);
                ssp[r] += __shfl_xor(ssp[r], off);
            }
        if (l16 == 0)
            #pragma unroll
            for (int r = 0; r < 4; ++r)
                partial[wv * 32 + mf * 16 + q * 4 + r] = make_float2(sp[r], ssp[r]);
    }
    __syncthreads();
    if (t < 32) {
        float sv = 0.f, ssv = 0.f;
        #pragma unroll
        for (int w = 0; w < 4; ++w) { sv += partial[w * 32 + t].x; ssv += partial[w * 32 + t].y; }
        float mu  = sv * (1.f / 256.f);
        float var = ssv * (1.f / 256.f) - mu * mu;
        stats[t] = make_float2(mu, rsqrtf(var + LN_EPS));
    }
    __syncthreads();

    #pragma unroll
    for (int mf = 0; mf < 2; ++mf)
        #pragma unroll
        for (int nf = 0; nf < 4; ++nf) {
            const int cg = wc + nf * 16 + l16;
            const float gm = gamma[cg], bt = beta[cg];
            #pragma unroll
            for (int r = 0; r < 4; ++r) {
                const int rl = mf * 16 + q * 4 + r;
                const float2 st = stats[rl];
                float v = (acc[mf][nf][r] - st.x) * st.y * gm + bt;
                preb[(size_t)(r0 + rl) * NH + cg] = f2bf(v);
            }
        }
}

// ---------------------------------------------------------------------------
extern "C" void kernel_launch(void* const* d_in, const int* in_sizes, int n_in,
                              void* d_out, int out_size, void* d_ws, size_t ws_size,
                              hipStream_t stream) {
    const float* X      = (const float*)d_in[0];
    const float* W_qkv  = (const float*)d_in[2];
    const float* W_o    = (const float*)d_in[3];
    const float* ln1_g  = (const float*)d_in[4];
    const float* ln1_b  = (const float*)d_in[5];
    const float* W_i    = (const float*)d_in[6];
    const float* W_out2 = (const float*)d_in[7];
    const float* ln2_g  = (const float*)d_in[8];
    const float* ln2_b  = (const float*)d_in[9];
    float* out = (float*)d_out;

    char* ws = (char*)d_ws;
    unsigned short* Xbf   = (unsigned short*)(ws);                 //  8.0 MB
    unsigned short* qkvb  = (unsigned short*)(ws + 8388608);       // 25.2 MB
    unsigned short* preb  = (unsigned short*)(ws + 58720256);      //  8.0 MB
    unsigned short* WqkvT = (unsigned short*)(ws + 67108864);
    unsigned short* WoT   = (unsigned short*)(ws + 67502080);
    unsigned short* WiT   = (unsigned short*)(ws + 67633152);
    unsigned short* Wo2T  = (unsigned short*)(ws + 68157440);
    unsigned short* interb = (unsigned short*)(ws);                // 33.5 MB alias (Xbf+qkvb dead)

    dim3 blk(256);
    hipLaunchKernelGGL(prep, dim3(768 + V * D / 4 / 256), blk, 0, stream,
                       X, Xbf, W_qkv, W_o, W_i, W_out2, WqkvT, WoT, WiT, Wo2T);

    hipLaunchKernelGGL((gemm128<D, THREE_NH, 0>), dim3(V / 128 * (THREE_NH / 128)), blk, 0, stream,
                       Xbf, WqkvT, qkvb);
    hipLaunchKernelGGL(attln, dim3(V / 32), blk, 0, stream,
                       qkvb, WoT, X, ln1_g, ln1_b, preb);
    hipLaunchKernelGGL((gemm128<D, IDIM, 1>), dim3(V / 128 * (IDIM / 128)), blk, 0, stream,
                       preb, WiT, interb);
    hipLaunchKernelGGL((gemm_ln<IDIM, true, true>), dim3(V / 32), blk, 0, stream,
                       interb, Wo2T, (const void*)preb, ln2_g, ln2_b, out, (unsigned short*)nullptr);
}

// Round 6
// 158.117 us; speedup vs baseline: 1.4198x; 1.0139x over previous
//
#include <hip/hip_runtime.h>
#include <math.h>

#define V 16384
#define D 256
#define NH 256
#define THREE_NH 768
#define IDIM 1024
#define LN_EPS 1e-12f
#define SCL 0.17677669529663687f

typedef short s16x8 __attribute__((ext_vector_type(8)));
typedef float f32x4 __attribute__((ext_vector_type(4)));

__device__ inline unsigned short f2bf(float f) {
    unsigned u = __float_as_uint(f);
    u += 0x7fffu + ((u >> 16) & 1u);          // RNE
    return (unsigned short)(u >> 16);
}
__device__ inline float bf2f(unsigned short s) {
    return __uint_as_float(((unsigned)s) << 16);
}

// Abramowitz-Stegun 7.1.26 erf, |err| < 1.5e-7 (invisible at bf16 tol)
__device__ inline float fast_erf(float x) {
    float ax = fabsf(x);
    float t  = 1.f / fmaf(0.3275911f, ax, 1.f);
    float p  = fmaf(fmaf(fmaf(fmaf(1.061405429f, t, -1.453152027f), t,
                              1.421413741f), t, -0.284496736f), t, 0.254829592f);
    float e  = 1.f - p * t * __expf(-ax * ax);
    return copysignf(e, x);
}

// async global->LDS, 16B per lane. LDS dest = wave-uniform base + lane*16.
__device__ inline void gl2lds16(const unsigned short* g, unsigned short* l) {
    __builtin_amdgcn_global_load_lds(
        (__attribute__((address_space(1))) void*)(g),
        (__attribute__((address_space(3))) void*)(l), 16, 0, 0);
}

// Stage ROWS_T x 64 bf16 tile (row-major, leading dim ldk) into LDS.
// 16B chunk c of row r stored at chunk slot c ^ (r&7).
template <int ROWS_T>
__device__ inline void stage(const unsigned short* __restrict__ src, size_t row0,
                             int ldk, int k0, unsigned short* lds, int wv, int lane) {
    constexpr int PER_WAVE = ROWS_T / 32;     // 1KB segments per wave
    #pragma unroll
    for (int i = 0; i < PER_WAVE; ++i) {
        const int seg = wv * PER_WAVE + i;
        const int r = seg * 8 + (lane >> 3);
        const int c = (lane & 7) ^ (r & 7);
        gl2lds16(src + (row0 + (size_t)r) * ldk + k0 + c * 8, lds + seg * 512);
    }
}

// read one 8-elem bf16 fragment (16B) for (row, chunk) from swizzled tile
__device__ inline s16x8 fragld(const unsigned short* lds, int row, int chunk) {
    return *(const s16x8*)&lds[row * 64 + ((chunk ^ (row & 7)) << 3)];
}

// ---------------------------------------------------------------------------
// prep: one launch for all conversions.
// ---------------------------------------------------------------------------
__global__ __launch_bounds__(256) void prep(const float* __restrict__ X,
                                            unsigned short* __restrict__ Xb,
                                            const float* __restrict__ Wqkv,
                                            const float* __restrict__ Wo,
                                            const float* __restrict__ Wi,
                                            const float* __restrict__ Wo2,
                                            unsigned short* __restrict__ WqkvT,
                                            unsigned short* __restrict__ WoT,
                                            unsigned short* __restrict__ WiT,
                                            unsigned short* __restrict__ Wo2T) {
    const int b = blockIdx.x, t = threadIdx.x;
    if (b >= 768) {
        int i = (b - 768) * 256 + t;
        float4 v = ((const float4*)X)[i];
        ushort4 o;
        o.x = f2bf(v.x); o.y = f2bf(v.y); o.z = f2bf(v.z); o.w = f2bf(v.w);
        ((ushort4*)Xb)[i] = o;
        return;
    }
    __shared__ float tile[32][33];
    const float* W; unsigned short* Wt; int K, N, bx, by;
    if (b < 192)      { W = Wqkv; Wt = WqkvT; K = 256;  N = 768;  bx = b & 7;          by = b >> 3; }
    else if (b < 256) { W = Wo;   Wt = WoT;   K = 256;  N = 256;  bx = (b - 192) & 7;  by = (b - 192) >> 3; }
    else if (b < 512) { W = Wi;   Wt = WiT;   K = 256;  N = 1024; bx = (b - 256) & 7;  by = (b - 256) >> 3; }
    else              { W = Wo2;  Wt = Wo2T;  K = 1024; N = 256;  bx = (b - 512) & 31; by = (b - 512) >> 5; }
    const int k0 = bx * 32, n0 = by * 32;
    #pragma unroll
    for (int p = 0; p < 4; ++p) {
        int idx = t + p * 256, r = idx >> 5, c = idx & 31;
        tile[r][c] = W[(size_t)(k0 + r) * N + n0 + c];
    }
    __syncthreads();
    #pragma unroll
    for (int p = 0; p < 4; ++p) {
        int idx = t + p * 256, r = idx >> 5, c = idx & 31;
        Wt[(size_t)(n0 + r) * K + k0 + c] = f2bf(tile[c][r]);
    }
}

// ---------------------------------------------------------------------------
// gemm128<K,N,EPI>: C = A @ Bt^T.  128x128 tile, BK=64, single-buffered,
// XCD row-band swizzle (R2-verified structure).
// ---------------------------------------------------------------------------
template <int K, int N, int EPI>
__global__ __launch_bounds__(256) void gemm128(const unsigned short* __restrict__ A,
                                               const unsigned short* __restrict__ Bt,
                                               unsigned short* __restrict__ C) {
    __shared__ unsigned short As[128 * 64];
    __shared__ unsigned short Bs[128 * 64];
    constexpr int NCOL = N / 128;
    const int b = blockIdx.x;
    const int idx = b >> 3;
    const int r0 = ((b & 7) * 16 + idx / NCOL) * 128;
    const int c0 = (idx % NCOL) * 128;
    const int t = threadIdx.x;
    const int wv = t >> 6, lane = t & 63, q = lane >> 4, l16 = lane & 15;
    const int wr = (wv >> 1) * 64, wc = (wv & 1) * 64;
    f32x4 acc[4][4] = {};

    for (int k0 = 0; k0 < K; k0 += 64) {
        __syncthreads();
        stage<128>(A,  (size_t)r0, K, k0, As, wv, lane);
        stage<128>(Bt, (size_t)c0, K, k0, Bs, wv, lane);
        __builtin_amdgcn_s_waitcnt(0);
        __syncthreads();
        #pragma unroll
        for (int kk2 = 0; kk2 < 2; ++kk2) {
            s16x8 af[4], bfr[4];
            #pragma unroll
            for (int mf = 0; mf < 4; ++mf)
                af[mf] = fragld(As, wr + mf * 16 + l16, kk2 * 4 + q);
            #pragma unroll
            for (int nf = 0; nf < 4; ++nf)
                bfr[nf] = fragld(Bs, wc + nf * 16 + l16, kk2 * 4 + q);
            #pragma unroll
            for (int mf = 0; mf < 4; ++mf)
                #pragma unroll
                for (int nf = 0; nf < 4; ++nf)
                    acc[mf][nf] = __builtin_amdgcn_mfma_f32_16x16x32_bf16(af[mf], bfr[nf], acc[mf][nf], 0, 0, 0);
        }
    }

    #pragma unroll
    for (int mf = 0; mf < 4; ++mf)
        #pragma unroll
        for (int nf = 0; nf < 4; ++nf) {
            const int cg = c0 + wc + nf * 16 + l16;
            #pragma unroll
            for (int r = 0; r < 4; ++r) {
                const int rg = r0 + wr + mf * 16 + q * 4 + r;
                float v = acc[mf][nf][r];
                if (EPI == 1) v = 0.5f * v * (1.f + fast_erf(v * 0.70710678118654752f));
                C[(size_t)rg * N + cg] = f2bf(v);
            }
        }
}

// ---------------------------------------------------------------------------
// ffn_ln: out = LN( gelu(pre @ WiT^T) @ Wo2T^T + pre ), fp32 out.  FUSED FFN:
// the 32x1024 intermediate never touches HBM (67 MB round-trip + 8 MB
// residual re-read + one kernel boundary eliminated).
// Per block (BM=32, 512 blocks, 65.3 KB LDS -> 2 blocks/CU):
//   Apre: preb rows staged ONCE (16 KB, fragld layout) — GEMM1 A + residual.
//   for nc in 0..3 (inter col chunks of 256):
//     GEMM1: 4x { stage<256> WiT chunk (32 KB) -> 16 MFMA } -> acc1
//     gelu(acc1) -> Pbuf (16 KB, fragld layout; wave wv writes tile wv)
//     GEMM2: 4x { stage<256> Wo2T k-slice (32 KB) -> 16 MFMA } -> acc2 (+=)
//   epilogue: acc2 + residual(from Apre LDS), fused row-LN (R2-verified code).
// All sub-structures are verbatim verified patterns (stage/fragld rounds,
// attln bridge-write, gemm_ln LN epilogue).
// ---------------------------------------------------------------------------
__global__ __launch_bounds__(256) void ffn_ln(const unsigned short* __restrict__ preb,
                                              const unsigned short* __restrict__ WiT,
                                              const unsigned short* __restrict__ Wo2T,
                                              const float* __restrict__ gamma,
                                              const float* __restrict__ beta,
                                              float* __restrict__ out) {
    __shared__ unsigned short Apre[32 * 64 * 4];   // 16 KB: 4 fragld k-chunk tiles
    __shared__ unsigned short Bs[256 * 64];        // 32 KB stage buffer (shared G1/G2)
    __shared__ unsigned short Pbuf[32 * 64 * 4];   // 16 KB: inter chunk, 4 k-sub tiles
    __shared__ float2 partial[4][32];
    __shared__ float2 stats[32];
    const int t = threadIdx.x, r0 = blockIdx.x * 32;
    const int wv = t >> 6, lane = t & 63, q = lane >> 4, l16 = lane & 15;
    const int wc = wv * 64;
    f32x4 acc2[2][4] = {};

    // stage A (preb rows, full K=256) once; wait folds into first round's drain
    #pragma unroll
    for (int kc = 0; kc < 4; ++kc)
        stage<32>(preb, (size_t)r0, 256, kc * 64, Apre + kc * 2048, wv, lane);

    for (int nc = 0; nc < 4; ++nc) {
        // ---- GEMM1: inter chunk [32 x 256], inter cols nc*256.. ----
        f32x4 acc1[2][4] = {};
        for (int k0 = 0; k0 < 256; k0 += 64) {
            __syncthreads();                     // Bs free (prev round / prev GEMM2 done)
            stage<256>(WiT, (size_t)nc * 256, 256, k0, Bs, wv, lane);
            __builtin_amdgcn_s_waitcnt(0);
            __syncthreads();
            const unsigned short* Ak = Apre + (k0 >> 6) * 2048;
            #pragma unroll
            for (int kk2 = 0; kk2 < 2; ++kk2) {
                s16x8 af[2], bfr[4];
                #pragma unroll
                for (int mf = 0; mf < 2; ++mf)
                    af[mf] = fragld(Ak, mf * 16 + l16, kk2 * 4 + q);
                #pragma unroll
                for (int nf = 0; nf < 4; ++nf)
                    bfr[nf] = fragld(Bs, wc + nf * 16 + l16, kk2 * 4 + q);
                #pragma unroll
                for (int mf = 0; mf < 2; ++mf)
                    #pragma unroll
                    for (int nf = 0; nf < 4; ++nf)
                        acc1[mf][nf] = __builtin_amdgcn_mfma_f32_16x16x32_bf16(af[mf], bfr[nf], acc1[mf][nf], 0, 0, 0);
            }
        }

        // ---- gelu -> Pbuf (fragld layout; wave wv owns tile wv) ----
        #pragma unroll
        for (int mf = 0; mf < 2; ++mf)
            #pragma unroll
            for (int nf = 0; nf < 4; ++nf)
                #pragma unroll
                for (int r = 0; r < 4; ++r) {
                    float v = acc1[mf][nf][r];
                    v = 0.5f * v * (1.f + fast_erf(v * 0.70710678118654752f));
                    const int i = mf * 16 + q * 4 + r;          // row 0..31
                    const int colc = wc + nf * 16 + l16;        // col in chunk 0..255
                    const int c8 = (colc >> 3) & 7;
                    Pbuf[wv * 2048 + i * 64 + ((c8 ^ (i & 7)) << 3) + (colc & 7)] = f2bf(v);
                }
        // cross-wave visibility handled by GEMM2's first-round barriers

        // ---- GEMM2: acc2 += inter_chunk @ Wo2T[:, nc*256+ks]^T ----
        for (int ks = 0; ks < 256; ks += 64) {
            __syncthreads();                     // orders Pbuf writes + Bs reuse
            stage<256>(Wo2T, 0, IDIM, nc * 256 + ks, Bs, wv, lane);
            __builtin_amdgcn_s_waitcnt(0);
            __syncthreads();
            const unsigned short* Pk = Pbuf + (ks >> 6) * 2048;
            #pragma unroll
            for (int kk2 = 0; kk2 < 2; ++kk2) {
                s16x8 af[2], bfr[4];
                #pragma unroll
                for (int mf = 0; mf < 2; ++mf)
                    af[mf] = fragld(Pk, mf * 16 + l16, kk2 * 4 + q);
                #pragma unroll
                for (int nf = 0; nf < 4; ++nf)
                    bfr[nf] = fragld(Bs, wc + nf * 16 + l16, kk2 * 4 + q);
                #pragma unroll
                for (int mf = 0; mf < 2; ++mf)
                    #pragma unroll
                    for (int nf = 0; nf < 4; ++nf)
                        acc2[mf][nf] = __builtin_amdgcn_mfma_f32_16x16x32_bf16(af[mf], bfr[nf], acc2[mf][nf], 0, 0, 0);
            }
        }
    }

    // ---- + residual (from Apre LDS, not global) ----
    #pragma unroll
    for (int mf = 0; mf < 2; ++mf)
        #pragma unroll
        for (int nf = 0; nf < 4; ++nf) {
            const int cg = wc + nf * 16 + l16;
            const int kb = cg >> 6, c8 = (cg >> 3) & 7, e = cg & 7;
            #pragma unroll
            for (int r = 0; r < 4; ++r) {
                const int i = mf * 16 + q * 4 + r;
                acc2[mf][nf][r] += bf2f(Apre[kb * 2048 + i * 64 + ((c8 ^ (i & 7)) << 3) + e]);
            }
        }

    // ---- fused row LN (R2-verified epilogue) ----
    #pragma unroll
    for (int mf = 0; mf < 2; ++mf) {
        float s[4] = {0.f, 0.f, 0.f, 0.f}, ss[4] = {0.f, 0.f, 0.f, 0.f};
        #pragma unroll
        for (int nf = 0; nf < 4; ++nf)
            #pragma unroll
            for (int r = 0; r < 4; ++r) {
                float v = acc2[mf][nf][r];
                s[r] += v; ss[r] += v * v;
            }
        #pragma unroll
        for (int off = 1; off < 16; off <<= 1)
            #pragma unroll
            for (int r = 0; r < 4; ++r) {
                s[r]  += __shfl_xor(s[r],  off);
                ss[r] += __shfl_xor(ss[r], off);
            }
        if (l16 == 0)
            #pragma unroll
            for (int r = 0; r < 4; ++r)
                partial[wv][mf * 16 + q * 4 + r] = make_float2(s[r], ss[r]);
    }
    __syncthreads();
    if (t < 32) {
        float s = 0.f, ss = 0.f;
        #pragma unroll
        for (int w = 0; w < 4; ++w) { s += partial[w][t].x; ss += partial[w][t].y; }
        float mu  = s * (1.f / 256.f);
        float var = ss * (1.f / 256.f) - mu * mu;
        stats[t] = make_float2(mu, rsqrtf(var + LN_EPS));
    }
    __syncthreads();

    #pragma unroll
    for (int mf = 0; mf < 2; ++mf)
        #pragma unroll
        for (int nf = 0; nf < 4; ++nf) {
            const int cg = wc + nf * 16 + l16;
            const float g = gamma[cg], b = beta[cg];
            #pragma unroll
            for (int r = 0; r < 4; ++r) {
                const int rl = mf * 16 + q * 4 + r;
                const float2 st = stats[rl];
                out[(size_t)(r0 + rl) * NH + cg] = (acc2[mf][nf][r] - st.x) * st.y * g + b;
            }
        }
}

// ---------------------------------------------------------------------------
// FUSED attention + W_o GEMM + LN1 — MFMA phase A (R5-verified).
// ---------------------------------------------------------------------------
__global__ __launch_bounds__(256) void attln(const unsigned short* __restrict__ qkv,
                                             const unsigned short* __restrict__ WoT,
                                             const float* __restrict__ X,
                                             const float* __restrict__ gamma,
                                             const float* __restrict__ beta,
                                             unsigned short* __restrict__ preb) {
    __shared__ unsigned short smem[25216];
    unsigned short* Ks = smem;                 // [0, 8192): h*1024 + j*32 + c*8
    unsigned short* Vt = smem + 8192;          // [8192,16384): h*1024 + d*32 + swz
    unsigned short* Ps = smem + 16384;         // [16384,24576): h*1024 + row*32 + swz
    unsigned short* at = smem;                 // phase B A-tile (overlays Ks)
    unsigned short* Bs = smem + 8192;          // phase B B-stage (overlays Vt+Ps)
    float2* partial = (float2*)(smem + 24576);
    float2* stats   = (float2*)(smem + 24576 + 512);

    const int g = blockIdx.x, t = threadIdx.x;
    const int wv = t >> 6, lane = t & 63, q = lane >> 4, l16 = lane & 15;
    const unsigned short* src = qkv + (size_t)g * 32 * THREE_NH;

    // ---- Q fragments direct from global ----
    s16x8 qf[2][2];
    #pragma unroll
    for (int hh = 0; hh < 2; ++hh)
        #pragma unroll
        for (int mf = 0; mf < 2; ++mf)
            qf[hh][mf] = *(const s16x8*)&src[(size_t)(mf * 16 + l16) * THREE_NH +
                                             (wv * 2 + hh) * 96 + q * 8];

    // ---- V 16B chunks to regs ----
    s16x8 vld[4];
    int vh[4], vj[4], vdc[4];
    #pragma unroll
    for (int i = 0; i < 4; ++i) {
        int cid = i * 256 + t;
        vh[i] = cid >> 7; int rem = cid & 127; vj[i] = rem >> 2; vdc[i] = rem & 3;
        vld[i] = *(const s16x8*)&src[(size_t)vj[i] * THREE_NH + vh[i] * 96 + 64 + vdc[i] * 8];
    }

    // ---- K async global->LDS ----
    #pragma unroll
    for (int i = 0; i < 4; ++i) {
        int ck = (wv * 4 + i) * 64 + lane;
        int h = ck >> 7, j = (ck >> 2) & 31, c = ck & 3;
        gl2lds16(src + (size_t)j * THREE_NH + h * 96 + 32 + c * 8, Ks + (wv * 4 + i) * 512);
    }

    // ---- Vt scatter: Vt[h][d][j], chunk slot (j>>3) ^ ((d>>2)&3) ----
    #pragma unroll
    for (int i = 0; i < 4; ++i)
        #pragma unroll
        for (int e = 0; e < 8; ++e) {
            int d = vdc[i] * 8 + e;
            Vt[vh[i] * 1024 + d * 32 + ((((vj[i] >> 3) ^ ((d >> 2) & 3))) << 3) + (vj[i] & 7)] =
                (unsigned short)vld[i][e];
        }

    __builtin_amdgcn_s_waitcnt(0);
    __syncthreads();

    // ---- scores: S[h] = Q @ K^T ----
    f32x4 sacc[2][2][2] = {};
    #pragma unroll
    for (int hh = 0; hh < 2; ++hh) {
        const int h = wv * 2 + hh;
        #pragma unroll
        for (int nf = 0; nf < 2; ++nf) {
            s16x8 kf = *(const s16x8*)&Ks[h * 1024 + (nf * 16 + l16) * 32 + q * 8];
            #pragma unroll
            for (int mf = 0; mf < 2; ++mf)
                sacc[hh][mf][nf] = __builtin_amdgcn_mfma_f32_16x16x32_bf16(
                    qf[hh][mf], kf, sacc[hh][mf][nf], 0, 0, 0);
        }
    }

    // ---- softmax (C-layout rows), deferred denominator ----
    float inv[2][2][4];
    #pragma unroll
    for (int hh = 0; hh < 2; ++hh) {
        const int h = wv * 2 + hh;
        #pragma unroll
        for (int mf = 0; mf < 2; ++mf)
            #pragma unroll
            for (int r = 0; r < 4; ++r) {
                float a0 = sacc[hh][mf][0][r], a1 = sacc[hh][mf][1][r];
                float m = fmaxf(a0, a1);
                m = fmaxf(m, __shfl_xor(m, 1));
                m = fmaxf(m, __shfl_xor(m, 2));
                m = fmaxf(m, __shfl_xor(m, 4));
                m = fmaxf(m, __shfl_xor(m, 8));
                float e0 = __expf((a0 - m) * SCL);
                float e1 = __expf((a1 - m) * SCL);
                float sm = e0 + e1;
                sm += __shfl_xor(sm, 1);
                sm += __shfl_xor(sm, 2);
                sm += __shfl_xor(sm, 4);
                sm += __shfl_xor(sm, 8);
                inv[hh][mf][r] = 1.f / sm;
                const int row = mf * 16 + q * 4 + r;
                const int base = h * 1024 + row * 32 + (l16 & 7);
                Ps[base + ((((l16 >> 3) ^ q)) << 3)]       = f2bf(e0);
                Ps[base + ((((2 + (l16 >> 3)) ^ q)) << 3)] = f2bf(e1);
            }
    }

    // ---- PV ----
    f32x4 oacc[2][2][2] = {};
    #pragma unroll
    for (int hh = 0; hh < 2; ++hh) {
        const int h = wv * 2 + hh;
        const int sw = (l16 >> 2) & 3;
        s16x8 pa[2], vb[2];
        #pragma unroll
        for (int mf = 0; mf < 2; ++mf)
            pa[mf] = *(const s16x8*)&Ps[h * 1024 + (mf * 16 + l16) * 32 + ((q ^ sw) << 3)];
        #pragma unroll
        for (int nf = 0; nf < 2; ++nf)
            vb[nf] = *(const s16x8*)&Vt[h * 1024 + (nf * 16 + l16) * 32 + ((q ^ sw) << 3)];
        #pragma unroll
        for (int mf = 0; mf < 2; ++mf)
            #pragma unroll
            for (int nf = 0; nf < 2; ++nf)
                oacc[hh][mf][nf] = __builtin_amdgcn_mfma_f32_16x16x32_bf16(
                    pa[mf], vb[nf], oacc[hh][mf][nf], 0, 0, 0);
    }
    __syncthreads();

    // ---- bridge: O * inv -> at (fragld layout) ----
    #pragma unroll
    for (int hh = 0; hh < 2; ++hh)
        #pragma unroll
        for (int mf = 0; mf < 2; ++mf)
            #pragma unroll
            for (int nf = 0; nf < 2; ++nf)
                #pragma unroll
                for (int r = 0; r < 4; ++r) {
                    float val = oacc[hh][mf][nf][r] * inv[hh][mf][r];
                    const int i = mf * 16 + q * 4 + r;
                    const int col = (wv * 2 + hh) * 32 + nf * 16 + l16;
                    const int kb = col >> 6, c = (col >> 3) & 7;
                    at[kb * 2048 + i * 64 + ((c ^ (i & 7)) << 3) + (col & 7)] = f2bf(val);
                }

    // ---- phase B: pre = LN(at @ WoT^T + X) ----
    const int wc = wv * 64;
    const int r0 = g * 32;
    f32x4 acc[2][4] = {};

    for (int k0 = 0; k0 < 256; k0 += 64) {
        __syncthreads();
        stage<256>(WoT, 0, 256, k0, Bs, wv, lane);
        __builtin_amdgcn_s_waitcnt(0);
        __syncthreads();
        const unsigned short* atk = at + (k0 >> 6) * 2048;
        #pragma unroll
        for (int kk2 = 0; kk2 < 2; ++kk2) {
            s16x8 af[2], bfr[4];
            #pragma unroll
            for (int mf = 0; mf < 2; ++mf)
                af[mf] = fragld(atk, mf * 16 + l16, kk2 * 4 + q);
            #pragma unroll
            for (int nf = 0; nf < 4; ++nf)
                bfr[nf] = fragld(Bs, wc + nf * 16 + l16, kk2 * 4 + q);
            #pragma unroll
            for (int mf = 0; mf < 2; ++mf)
                #pragma unroll
                for (int nf = 0; nf < 4; ++nf)
                    acc[mf][nf] = __builtin_amdgcn_mfma_f32_16x16x32_bf16(af[mf], bfr[nf], acc[mf][nf], 0, 0, 0);
        }
    }

    #pragma unroll
    for (int mf = 0; mf < 2; ++mf)
        #pragma unroll
        for (int nf = 0; nf < 4; ++nf) {
            const int cg = wc + nf * 16 + l16;
            #pragma unroll
            for (int r = 0; r < 4; ++r)
                acc[mf][nf][r] += X[(size_t)(r0 + mf * 16 + q * 4 + r) * NH + cg];
        }

    #pragma unroll
    for (int mf = 0; mf < 2; ++mf) {
        float sp[4] = {0.f, 0.f, 0.f, 0.f}, ssp[4] = {0.f, 0.f, 0.f, 0.f};
        #pragma unroll
        for (int nf = 0; nf < 4; ++nf)
            #pragma unroll
            for (int r = 0; r < 4; ++r) {
                float v = acc[mf][nf][r];
                sp[r] += v; ssp[r] += v * v;
            }
        #pragma unroll
        for (int off = 1; off < 16; off <<= 1)
            #pragma unroll
            for (int r = 0; r < 4; ++r) {
                sp[r]  += __shfl_xor(sp[r],  off);
                ssp[r] += __shfl_xor(ssp[r], off);
            }
        if (l16 == 0)
            #pragma unroll
            for (int r = 0; r < 4; ++r)
                partial[wv * 32 + mf * 16 + q * 4 + r] = make_float2(sp[r], ssp[r]);
    }
    __syncthreads();
    if (t < 32) {
        float sv = 0.f, ssv = 0.f;
        #pragma unroll
        for (int w = 0; w < 4; ++w) { sv += partial[w * 32 + t].x; ssv += partial[w * 32 + t].y; }
        float mu  = sv * (1.f / 256.f);
        float var = ssv * (1.f / 256.f) - mu * mu;
        stats[t] = make_float2(mu, rsqrtf(var + LN_EPS));
    }
    __syncthreads();

    #pragma unroll
    for (int mf = 0; mf < 2; ++mf)
        #pragma unroll
        for (int nf = 0; nf < 4; ++nf) {
            const int cg = wc + nf * 16 + l16;
            const float gm = gamma[cg], bt = beta[cg];
            #pragma unroll
            for (int r = 0; r < 4; ++r) {
                const int rl = mf * 16 + q * 4 + r;
                const float2 st = stats[rl];
                float v = (acc[mf][nf][r] - st.x) * st.y * gm + bt;
                preb[(size_t)(r0 + rl) * NH + cg] = f2bf(v);
            }
        }
}

// ---------------------------------------------------------------------------
extern "C" void kernel_launch(void* const* d_in, const int* in_sizes, int n_in,
                              void* d_out, int out_size, void* d_ws, size_t ws_size,
                              hipStream_t stream) {
    const float* X      = (const float*)d_in[0];
    const float* W_qkv  = (const float*)d_in[2];
    const float* W_o    = (const float*)d_in[3];
    const float* ln1_g  = (const float*)d_in[4];
    const float* ln1_b  = (const float*)d_in[5];
    const float* W_i    = (const float*)d_in[6];
    const float* W_out2 = (const float*)d_in[7];
    const float* ln2_g  = (const float*)d_in[8];
    const float* ln2_b  = (const float*)d_in[9];
    float* out = (float*)d_out;

    char* ws = (char*)d_ws;
    unsigned short* Xbf   = (unsigned short*)(ws);                 //  8.0 MB
    unsigned short* qkvb  = (unsigned short*)(ws + 8388608);       // 25.2 MB
    unsigned short* preb  = (unsigned short*)(ws + 58720256);      //  8.0 MB
    unsigned short* WqkvT = (unsigned short*)(ws + 67108864);
    unsigned short* WoT   = (unsigned short*)(ws + 67502080);
    unsigned short* WiT   = (unsigned short*)(ws + 67633152);
    unsigned short* Wo2T  = (unsigned short*)(ws + 68157440);

    dim3 blk(256);
    hipLaunchKernelGGL(prep, dim3(768 + V * D / 4 / 256), blk, 0, stream,
                       X, Xbf, W_qkv, W_o, W_i, W_out2, WqkvT, WoT, WiT, Wo2T);

    hipLaunchKernelGGL((gemm128<D, THREE_NH, 0>), dim3(V / 128 * (THREE_NH / 128)), blk, 0, stream,
                       Xbf, WqkvT, qkvb);
    hipLaunchKernelGGL(attln, dim3(V / 32), blk, 0, stream,
                       qkvb, WoT, X, ln1_g, ln1_b, preb);
    hipLaunchKernelGGL(ffn_ln, dim3(V / 32), blk, 0, stream,
                       preb, WiT, Wo2T, ln2_g, ln2_b, out);
}